// Round 11
// baseline (948.495 us; speedup 1.0000x reference)
//
#include <hip/hip_runtime.h>
#include <cfloat>
#include <cmath>

#define NN 40000
#define DIN 3000
#define NE 640000
#define ET (NE + NN)   // edges incl. self-loops = 680000

#define ROWS 128      // rows per block in k_enc0 (= threads; 1 row/thread)
#define NCH 5         // split-K chunks
#define KCH 600       // K per chunk
#define KC 40         // K per LDS stage
#define NST 15        // stages per chunk (KCH/KC)
#define XQ 1280       // float4 quads per x stage (128 rows x 10 quads)

__device__ __forceinline__ float lrelu(float x) { return x >= 0.f ? x : 0.2f * x; }
__device__ __forceinline__ float elu(float x)   { return x > 0.f ? x : expm1f(x); }

// ---------------- Kernel A: partial = x @ e0_w (split-K x5) ----------------
// Thread = 1 row x 32 cols (acc = 8 float4). x staged via global_load_lds
// (width 16, no VGPR staging state) into TRANSPOSED-LINEAR layout [q][r]:
// lds slot qq = q*128 + r, so compute read (s*128+tid)*16B is 64 contiguous
// 16B slots per wave = HW-minimum, conflict-free. Double-buffered: issue
// chunk+1 loads BEFORE compute, __syncthreads drains vmcnt after -> HBM busy
// during compute. w read DIRECT from global (wave-uniform index -> scalar
// s_load path, no LDS instr). LDS instrs/s-step: 33 -> 1.
__global__ __launch_bounds__(128, 4) void k_enc0(
    const float* __restrict__ x, const float* __restrict__ w,
    float* __restrict__ partial)   // [NCH][NN][32]
{
    __shared__ float xt[2][XQ * 4];    // 2 x 20 KB
    const int tid = threadIdx.x;       // 0..127; row = row0 + tid
    const int row0 = blockIdx.x * ROWS;
    const int kb = blockIdx.y * KCH;

    auto issue_x = [&](int buf, int kc) {
        #pragma unroll
        for (int it = 0; it < 10; it++) {
            int qq = it * 128 + tid;       // linear quad slot
            int r = qq & 127, q = qq >> 7; // row, quad-within-row
            int grow = row0 + r; if (grow > NN - 1) grow = NN - 1;
            const float* gp = &x[(size_t)grow * DIN + kc + q * 4];
            __builtin_amdgcn_global_load_lds(
                (const __attribute__((address_space(1))) void*)gp,
                (__attribute__((address_space(3))) void*)&xt[buf][qq * 4],
                16, 0, 0);
        }
    };

    float4 acc[8];
    #pragma unroll
    for (int c4 = 0; c4 < 8; c4++) acc[c4] = make_float4(0.f, 0.f, 0.f, 0.f);

    issue_x(0, kb);
    __syncthreads();   // drains vmcnt -> buffer 0 ready

    for (int ch = 0; ch < NST; ch++) {
        const int cur = ch & 1;
        if (ch + 1 < NST) issue_x(cur ^ 1, kb + (ch + 1) * KC);
        const int kcc = kb + ch * KC;
        const float* xb = &xt[cur][0];

        #pragma unroll
        for (int s = 0; s < KC / 4; s++) {
            float4 xa = *(const float4*)&xb[(s * 128 + tid) * 4];
            #pragma unroll
            for (int i = 0; i < 4; i++) {
                float xs = (i == 0) ? xa.x : (i == 1) ? xa.y : (i == 2) ? xa.z : xa.w;
                const float* wr = &w[(size_t)(kcc + s * 4 + i) * 32];
                #pragma unroll
                for (int c4 = 0; c4 < 8; c4++) {
                    float4 wv = *(const float4*)&wr[c4 * 4];   // uniform -> s_load
                    acc[c4].x += xs * wv.x;
                    acc[c4].y += xs * wv.y;
                    acc[c4].z += xs * wv.z;
                    acc[c4].w += xs * wv.w;
                }
            }
        }
        __syncthreads();   // compute done + next-chunk loads drained
    }

    const int row = row0 + tid;
    if (row < NN) {
        size_t o = ((size_t)blockIdx.y * NN + row) * 32;
        #pragma unroll
        for (int c4 = 0; c4 < 8; c4++)
            *(float4*)&partial[o + c4 * 4] = acc[c4];
    }
}

// ------- Kernel A2: h = elu(bn(sum partials + e0_b)) -------
// h aliases partial chunk 4; each thread reads its own quad then overwrites -> safe.
__global__ void k_enc0_fin(
    const float* __restrict__ partial,
    const float* __restrict__ b, const float* __restrict__ g,
    const float* __restrict__ beta, const float* __restrict__ m,
    const float* __restrict__ v, float* __restrict__ h)
{
    int q = blockIdx.x * 256 + threadIdx.x;   // quad index over [NN*8)
    if (q >= NN * 8) return;
    int c = (q & 7) * 4;
    float4 s = make_float4(0.f, 0.f, 0.f, 0.f);
    #pragma unroll
    for (int ch = 0; ch < NCH; ch++) {
        float4 p = ((const float4*)partial)[(size_t)ch * NN * 8 + q];
        s.x += p.x; s.y += p.y; s.z += p.z; s.w += p.w;
    }
    float sc0 = g[c+0] * rsqrtf(v[c+0] + 1e-3f);
    float sc1 = g[c+1] * rsqrtf(v[c+1] + 1e-3f);
    float sc2 = g[c+2] * rsqrtf(v[c+2] + 1e-3f);
    float sc3 = g[c+3] * rsqrtf(v[c+3] + 1e-3f);
    float4 o;
    o.x = elu((s.x + b[c+0]) * sc0 + (beta[c+0] - m[c+0] * sc0));
    o.y = elu((s.y + b[c+1]) * sc1 + (beta[c+1] - m[c+1] * sc1));
    o.z = elu((s.z + b[c+2]) * sc2 + (beta[c+2] - m[c+2] * sc2));
    o.w = elu((s.w + b[c+3]) * sc3 + (beta[c+3] - m[c+3] * sc3));
    ((float4*)h)[q] = o;
}

// ------------- Kernel B: feat_x, hw1, attention scalars, init GAT1 atomics -------------
__global__ void k_enc1_prep(
    const float* __restrict__ h,
    const float* __restrict__ e1w, const float* __restrict__ e1b,
    const float* __restrict__ e1g, const float* __restrict__ e1beta,
    const float* __restrict__ e1m, const float* __restrict__ e1v,
    const float* __restrict__ g1w, const float* __restrict__ g1as,
    const float* __restrict__ g1ad,
    float* __restrict__ out_fx, float* __restrict__ hw1,
    float* __restrict__ s1src, float* __restrict__ s1dst,
    float* __restrict__ z1, float* __restrict__ acc1)
{
    int row = blockIdx.x * 256 + threadIdx.x;
    if (row >= NN) return;
    float hr[32];
    #pragma unroll
    for (int k = 0; k < 32; k++) hr[k] = h[(size_t)row * 32 + k];
    float fx[20];
    for (int c = 0; c < 20; c++) {
        float s = e1b[c];
        for (int k = 0; k < 32; k++) s += hr[k] * e1w[k * 20 + c];
        float sc = e1g[c] * rsqrtf(e1v[c] + 1e-3f);
        s = (s - e1m[c]) * sc + e1beta[c];
        fx[c] = elu(s);
        out_fx[(size_t)row * 20 + c] = fx[c];
    }
    float ss = 0.f, sd = 0.f;
    for (int c = 0; c < 64; c++) {
        float s = 0.f;
        for (int k = 0; k < 20; k++) s += fx[k] * g1w[k * 64 + c];
        hw1[(size_t)row * 64 + c] = s;
        ss += s * g1as[c];
        sd += s * g1ad[c];
        acc1[(size_t)row * 64 + c] = 0.f;
    }
    s1src[row] = ss; s1dst[row] = sd;
    z1[row] = 0.f;
}

// ------------- Kernel D: GAT1 numerator/denominator accumulate (64 lanes/edge) -------------
// softmax is shift-invariant: use exp(al) directly (logits bounded ~|3|), skip max pass.
__global__ __launch_bounds__(256) void k_gat1_acc(const int* __restrict__ ei,
    const float* __restrict__ s1src, const float* __restrict__ s1dst,
    const float* __restrict__ hw1,
    float* __restrict__ z1, float* __restrict__ acc1)
{
    int t = blockIdx.x * 256 + threadIdx.x;
    int lane = t & 63;
    int e = t >> 6;
    if (e >= ET) return;
    int s, d;
    if (e < NE) { s = ei[e]; d = ei[NE + e]; } else { s = d = e - NE; }
    float al = lrelu(s1src[s] + s1dst[d]);
    float ex = expf(al);
    if (lane == 0) atomicAdd(&z1[d], ex);
    atomicAdd(&acc1[(size_t)d * 64 + lane], ex * hw1[(size_t)s * 64 + lane]);
}

// ------------- Kernel E: normalize GAT1, BN+ReLU -> c; hw_m/hw_v + scalars; init atomics -------------
__global__ void k_gat1_norm(
    const float* __restrict__ acc1, const float* __restrict__ z1,
    const float* __restrict__ g1b,
    const float* __restrict__ bncg, const float* __restrict__ bncbeta,
    const float* __restrict__ bncm, const float* __restrict__ bncv,
    const float* __restrict__ gmw, const float* __restrict__ gmas, const float* __restrict__ gmad,
    const float* __restrict__ gvw, const float* __restrict__ gvas, const float* __restrict__ gvad,
    float* __restrict__ hwm, float* __restrict__ hwv,
    float* __restrict__ smsrc, float* __restrict__ smdst,
    float* __restrict__ svsrc, float* __restrict__ svdst,
    float* __restrict__ zm, float* __restrict__ zv,
    float* __restrict__ accm, float* __restrict__ accv)
{
    int row = blockIdx.x * 256 + threadIdx.x;
    if (row >= NN) return;
    float zi = 1.f / (z1[row] + 1e-16f);
    float c[64];
    for (int f = 0; f < 64; f++) {
        float val = acc1[(size_t)row * 64 + f] * zi + g1b[f];
        float sc = bncg[f] * rsqrtf(bncv[f] + 1e-5f);
        val = (val - bncm[f]) * sc + bncbeta[f];
        c[f] = val > 0.f ? val : 0.f;
    }
    float ssm = 0.f, sdm = 0.f, ssv = 0.f, sdv = 0.f;
    for (int o = 0; o < 8; o++) {
        float sm = 0.f, sv = 0.f;
        for (int k = 0; k < 64; k++) {
            sm += c[k] * gmw[k * 8 + o];
            sv += c[k] * gvw[k * 8 + o];
        }
        hwm[(size_t)row * 8 + o] = sm; hwv[(size_t)row * 8 + o] = sv;
        ssm += sm * gmas[o]; sdm += sm * gmad[o];
        ssv += sv * gvas[o]; sdv += sv * gvad[o];
        accm[(size_t)row * 8 + o] = 0.f; accv[(size_t)row * 8 + o] = 0.f;
    }
    smsrc[row] = ssm; smdst[row] = sdm;
    svsrc[row] = ssv; svdst[row] = sdv;
    zm[row] = 0.f;
    zv[row] = 0.f;
}

// ------------- Kernel G: mu/logvar GAT accumulate (8 lanes/edge), no max pass -------------
__global__ __launch_bounds__(256) void k_gat23_acc(const int* __restrict__ ei,
    const float* __restrict__ smsrc, const float* __restrict__ smdst,
    const float* __restrict__ svsrc, const float* __restrict__ svdst,
    const float* __restrict__ hwm, const float* __restrict__ hwv,
    float* __restrict__ zm, float* __restrict__ accm,
    float* __restrict__ zv, float* __restrict__ accv)
{
    int t = blockIdx.x * 256 + threadIdx.x;
    int lane = t & 7;
    int e = t >> 3;
    if (e >= ET) return;
    int s, d;
    if (e < NE) { s = ei[e]; d = ei[NE + e]; } else { s = d = e - NE; }
    float am = lrelu(smsrc[s] + smdst[d]);
    float exm = expf(am);
    if (lane == 0) atomicAdd(&zm[d], exm);
    atomicAdd(&accm[(size_t)d * 8 + lane], exm * hwm[(size_t)s * 8 + lane]);
    float av = lrelu(svsrc[s] + svdst[d]);
    float exv = expf(av);
    if (lane == 0) atomicAdd(&zv[d], exv);
    atomicAdd(&accv[(size_t)d * 8 + lane], exv * hwv[(size_t)s * 8 + lane]);
}

// ------------- Kernel H: mu/logvar/gnn_z/z, decoder L0, student-t q -------------
__global__ void k_final(
    const float* __restrict__ accm, const float* __restrict__ zm, const float* __restrict__ gmb,
    const float* __restrict__ accv, const float* __restrict__ zv, const float* __restrict__ gvb,
    const float* __restrict__ epsin, const float* __restrict__ fx_out,
    const float* __restrict__ d0w, const float* __restrict__ d0b,
    const float* __restrict__ d0g, const float* __restrict__ d0beta,
    const float* __restrict__ d0m, const float* __restrict__ d0v,
    const float* __restrict__ cluster,
    float* __restrict__ out_z, float* __restrict__ out_mu, float* __restrict__ out_lv,
    float* __restrict__ out_q, float* __restrict__ out_gz, float* __restrict__ dbuf)
{
    int row = blockIdx.x * 256 + threadIdx.x;
    if (row >= NN) return;
    float zvec[28];
    #pragma unroll
    for (int k = 0; k < 20; k++) zvec[k] = fx_out[(size_t)row * 20 + k];
    float zim = 1.f / (zm[row] + 1e-16f);
    float ziv = 1.f / (zv[row] + 1e-16f);
    #pragma unroll
    for (int o = 0; o < 8; o++) {
        float mu = accm[(size_t)row * 8 + o] * zim + gmb[o];
        float lv = accv[(size_t)row * 8 + o] * ziv + gvb[o];
        float gz = epsin[(size_t)row * 8 + o] * expf(lv) + mu;
        out_mu[(size_t)row * 8 + o] = mu;
        out_lv[(size_t)row * 8 + o] = lv;
        out_gz[(size_t)row * 8 + o] = gz;
        zvec[20 + o] = gz;
    }
    #pragma unroll
    for (int k = 0; k < 28; k++) out_z[(size_t)row * 28 + k] = zvec[k];
    // decoder L0: elu(bn(z @ d0_w + d0_b))
    for (int c = 0; c < 32; c++) {
        float s = d0b[c];
        for (int k = 0; k < 28; k++) s += zvec[k] * d0w[k * 32 + c];
        float sc = d0g[c] * rsqrtf(d0v[c] + 1e-3f);
        s = (s - d0m[c]) * sc + d0beta[c];
        dbuf[(size_t)row * 32 + c] = elu(s);
    }
    // student-t q
    float zz = 0.f;
    #pragma unroll
    for (int k = 0; k < 28; k++) zz += zvec[k] * zvec[k];
    float qv[15], qs = 0.f;
    for (int j = 0; j < 15; j++) {
        float cc = 0.f, zc = 0.f;
        for (int k = 0; k < 28; k++) {
            float cv = cluster[j * 28 + k];
            cc += cv * cv; zc += zvec[k] * cv;
        }
        float sq = zz + cc - 2.f * zc;
        if (sq < 0.f) sq = 0.f;
        float qb = 1.f / (1.f + sq * (1.f / 0.9f) + 1e-8f);
        qb = powf(qb, 0.95f);
        qv[j] = qb; qs += qb;
    }
    float qi = 1.f / qs;
    #pragma unroll
    for (int j = 0; j < 15; j++) out_q[(size_t)row * 15 + j] = qv[j] * qi;
}

// ------------- Kernel I: de_feat = d @ out_w + out_b -------------
#define DQ 750   // DIN/4 quads per row
__global__ __launch_bounds__(256) void k_dec_out(
    const float* __restrict__ dbuf, const float* __restrict__ ow,
    const float* __restrict__ ob, float* __restrict__ out_de)
{
    __shared__ float4 wt[32 * 64];   // [k][quad]
    __shared__ float  dt[64 * 32];   // [row][k]
    const int tid = threadIdx.x;
    const int cq0 = blockIdx.x * 64;      // quad base in output row
    const int row0 = blockIdx.y * 64;

    // load w tile: 32 k-rows x 64 quads
    #pragma unroll
    for (int i = 0; i < 8; i++) {
        int t = tid + i * 256;            // 0..2047
        int k = t >> 6, lq = t & 63;
        int gq = cq0 + lq;
        wt[t] = (gq < DQ) ? ((const float4*)ow)[(size_t)k * DQ + gq]
                          : make_float4(0.f, 0.f, 0.f, 0.f);
    }
    // load d tile: 64 rows x 32 = 512 float4
    #pragma unroll
    for (int i = 0; i < 2; i++) {
        int t = tid + i * 256;
        ((float4*)dt)[t] = ((const float4*)dbuf)[(size_t)row0 * 8 + t];
    }
    __syncthreads();

    const int qid = tid & 63;
    const int rg  = tid >> 6;             // wave-uniform row group (0..3)
    const int q   = cq0 + qid;
    const bool valid = q < DQ;

    float4 acc[16];
    #pragma unroll
    for (int r = 0; r < 16; r++) acc[r] = make_float4(0.f, 0.f, 0.f, 0.f);

    #pragma unroll
    for (int k4 = 0; k4 < 8; k4++) {
        float4 w0 = wt[(k4 * 4 + 0) * 64 + qid];
        float4 w1 = wt[(k4 * 4 + 1) * 64 + qid];
        float4 w2 = wt[(k4 * 4 + 2) * 64 + qid];
        float4 w3 = wt[(k4 * 4 + 3) * 64 + qid];
        #pragma unroll
        for (int r = 0; r < 16; r++) {
            float4 dq = *(const float4*)&dt[(rg * 16 + r) * 32 + k4 * 4]; // broadcast
            acc[r].x += dq.x * w0.x; acc[r].y += dq.x * w0.y;
            acc[r].z += dq.x * w0.z; acc[r].w += dq.x * w0.w;
            acc[r].x += dq.y * w1.x; acc[r].y += dq.y * w1.y;
            acc[r].z += dq.y * w1.z; acc[r].w += dq.y * w1.w;
            acc[r].x += dq.z * w2.x; acc[r].y += dq.z * w2.y;
            acc[r].z += dq.z * w2.z; acc[r].w += dq.z * w2.w;
            acc[r].x += dq.w * w3.x; acc[r].y += dq.w * w3.y;
            acc[r].z += dq.w * w3.z; acc[r].w += dq.w * w3.w;
        }
    }

    if (valid) {
        float4 bq = ((const float4*)ob)[q];
        #pragma unroll
        for (int r = 0; r < 16; r++) {
            float4 o;
            o.x = acc[r].x + bq.x; o.y = acc[r].y + bq.y;
            o.z = acc[r].z + bq.z; o.w = acc[r].w + bq.w;
            ((float4*)out_de)[(size_t)(row0 + rg * 16 + r) * DQ + q] = o;
        }
    }
}

extern "C" void kernel_launch(void* const* d_in, const int* in_sizes, int n_in,
                              void* d_out, int out_size, void* d_ws, size_t ws_size,
                              hipStream_t stream) {
    const float* x      = (const float*)d_in[0];
    const int*   ei     = (const int*)  d_in[1];
    const float* e0_w   = (const float*)d_in[2];
    const float* e0_b   = (const float*)d_in[3];
    const float* e0_g   = (const float*)d_in[4];
    const float* e0_be  = (const float*)d_in[5];
    const float* e0_m   = (const float*)d_in[6];
    const float* e0_v   = (const float*)d_in[7];
    const float* e1_w   = (const float*)d_in[8];
    const float* e1_b   = (const float*)d_in[9];
    const float* e1_g   = (const float*)d_in[10];
    const float* e1_be  = (const float*)d_in[11];
    const float* e1_m   = (const float*)d_in[12];
    const float* e1_v   = (const float*)d_in[13];
    const float* g1_w   = (const float*)d_in[14];
    const float* g1_as  = (const float*)d_in[15];
    const float* g1_ad  = (const float*)d_in[16];
    const float* g1_b   = (const float*)d_in[17];
    const float* bnc_g  = (const float*)d_in[18];
    const float* bnc_be = (const float*)d_in[19];
    const float* bnc_m  = (const float*)d_in[20];
    const float* bnc_v  = (const float*)d_in[21];
    const float* gm_w   = (const float*)d_in[22];
    const float* gm_as  = (const float*)d_in[23];
    const float* gm_ad  = (const float*)d_in[24];
    const float* gm_b   = (const float*)d_in[25];
    const float* gv_w   = (const float*)d_in[26];
    const float* gv_as  = (const float*)d_in[27];
    const float* gv_ad  = (const float*)d_in[28];
    const float* gv_b   = (const float*)d_in[29];
    const float* d0_w   = (const float*)d_in[30];
    const float* d0_b   = (const float*)d_in[31];
    const float* d0_g   = (const float*)d_in[32];
    const float* d0_be  = (const float*)d_in[33];
    const float* d0_m   = (const float*)d_in[34];
    const float* d0_v   = (const float*)d_in[35];
    const float* out_w  = (const float*)d_in[36];
    const float* out_b  = (const float*)d_in[37];
    const float* cluster= (const float*)d_in[38];
    const float* epsin  = (const float*)d_in[39];

    float* out = (float*)d_out;
    // output offsets (floats), return order: z, mu, logvar, de_feat, q, feat_x, gnn_z
    float* out_z  = out;
    float* out_mu = out + (size_t)NN * 28;
    float* out_lv = out + (size_t)NN * 36;
    float* out_de = out + (size_t)NN * 44;
    float* out_q  = out + (size_t)NN * 44 + (size_t)NN * DIN;
    float* out_fx = out + (size_t)NN * 59 + (size_t)NN * DIN;
    float* out_gz = out + (size_t)NN * 79 + (size_t)NN * DIN;

    float* ws = (float*)d_ws;
    const size_t n = NN;
    // enc0: partial[5][N][32] = ws[0..160N); chunk-4 slice aliases hbuf.
    float* partial = ws;
    // phase-1 layout
    float* hw1   = ws;                 // 64N
    float* acc1  = ws + 64 * n;        // 64N
    float* hbuf  = ws + 128 * n;       // 32N (h, later reused as dbuf)
    float* s1src = ws + 160 * n;
    float* s1dst = ws + 161 * n;
    float* z1    = ws + 162 * n;
    // phase-2 layout (reuses hw1's 64N block after GAT1 is done)
    float* hwm   = ws;                 // 8N
    float* hwv   = ws + 8 * n;         // 8N
    float* smsrc = ws + 16 * n;
    float* smdst = ws + 17 * n;
    float* svsrc = ws + 18 * n;
    float* svdst = ws + 19 * n;
    float* zm    = ws + 20 * n;
    float* zv    = ws + 21 * n;
    float* accm  = ws + 24 * n;        // 8N
    float* accv  = ws + 32 * n;        // 8N
    float* dbuf  = hbuf;               // 32N

    const int NB_ROWS = (NN + 255) / 256;  // 157

    dim3 enc0_grid((NN + ROWS - 1) / ROWS, NCH);   // 313 x 5
    k_enc0<<<enc0_grid, 128, 0, stream>>>(x, e0_w, partial);
    k_enc0_fin<<<(NN * 8 + 255) / 256, 256, 0, stream>>>(partial, e0_b, e0_g, e0_be,
                                                         e0_m, e0_v, hbuf);
    k_enc1_prep<<<NB_ROWS, 256, 0, stream>>>(hbuf, e1_w, e1_b, e1_g, e1_be, e1_m, e1_v,
                                             g1_w, g1_as, g1_ad,
                                             out_fx, hw1, s1src, s1dst, z1, acc1);
    k_gat1_acc<<<(ET * 64) / 256, 256, 0, stream>>>(ei, s1src, s1dst, hw1, z1, acc1);
    k_gat1_norm<<<NB_ROWS, 256, 0, stream>>>(acc1, z1, g1_b, bnc_g, bnc_be, bnc_m, bnc_v,
                                             gm_w, gm_as, gm_ad, gv_w, gv_as, gv_ad,
                                             hwm, hwv, smsrc, smdst, svsrc, svdst,
                                             zm, zv, accm, accv);
    k_gat23_acc<<<(ET * 8) / 256, 256, 0, stream>>>(ei, smsrc, smdst, svsrc, svdst,
                                                    hwm, hwv, zm, accm, zv, accv);
    k_final<<<NB_ROWS, 256, 0, stream>>>(accm, zm, gm_b, accv, zv, gv_b, epsin, out_fx,
                                         d0_w, d0_b, d0_g, d0_be, d0_m, d0_v, cluster,
                                         out_z, out_mu, out_lv, out_q, out_gz, dbuf);
    dim3 dec_grid((DQ + 63) / 64, NN / 64);
    k_dec_out<<<dec_grid, 256, 0, stream>>>(dbuf, out_w, out_b, out_de);
}

// Round 12
// 731.448 us; speedup vs baseline: 1.2967x; 1.2967x over previous
//
#include <hip/hip_runtime.h>
#include <cfloat>
#include <cmath>

#define NN 40000
#define DIN 3000
#define NE 640000
#define ET (NE + NN)   // edges incl. self-loops = 680000

#define NCH 2         // split-K chunks for enc0
#define KPAD 3072     // padded K (2 x 1536)
#define KCHUNK 1536   // K per chunk
#define NSTG 12       // 128-k stages per chunk

typedef __attribute__((ext_vector_type(8))) short short8;
typedef __attribute__((ext_vector_type(4))) float f32x4;

__device__ __forceinline__ float lrelu(float x) { return x >= 0.f ? x : 0.2f * x; }
__device__ __forceinline__ float elu(float x)   { return x > 0.f ? x : expm1f(x); }
__device__ __forceinline__ unsigned f2bf(float f) {
    unsigned u = __float_as_uint(f);
    return (u + 0x7FFFu + ((u >> 16) & 1u)) >> 16;   // RNE fp32->bf16
}

// ------- Kernel A0: wTb[32][3072] bf16 = transpose(w[3000][32]), zero-padded -------
__global__ void k_wprep(const float* __restrict__ w, unsigned short* __restrict__ wTb)
{
    int id = blockIdx.x * 256 + threadIdx.x;
    if (id >= 32 * KPAD) return;
    int c = id / KPAD, k = id - c * KPAD;
    float v = (k < DIN) ? w[(size_t)k * 32 + c] : 0.f;
    wTb[id] = (unsigned short)f2bf(v);
}

// ---------------- Kernel A: partial = x @ e0_w via MFMA bf16 ----------------
// Block = 256 thr = 4 waves; tile 64 rows x 32 cols; wave = 16 rows x 32 cols
// (2 MFMA col-tiles, acc 2 x f32x4). Split-K x2 (1536 each, zero-padded).
// Per 128-k stage: x fp32 -> bf16 -> LDS [64][128] XOR-swizzled (^((row&7)<<4));
// w bf16 staged [col][128] same swizzle. Frag layouts (CDNA): A lane=row(l&15),
// k=(l>>4)*8+j; B lane=col(l&15); D col=l&15,row=(l>>4)*4+reg (m89-verified).
__global__ __launch_bounds__(256) void k_enc0(
    const float* __restrict__ x, const unsigned short* __restrict__ wTb,
    float* __restrict__ partial)   // [NCH][NN][32]
{
    __shared__ __align__(16) char xb[64 * 256];   // 16 KB: bf16 [64 r][128 k] swz
    __shared__ __align__(16) char wb[32 * 256];   //  8 KB: bf16 [32 c][128 k] swz
    const int tid = threadIdx.x;
    const int wid = tid >> 6;
    const int l = tid & 63;
    const int row0 = blockIdx.x * 64;
    const int kb = blockIdx.y * KCHUNK;

    f32x4 acc0 = {0.f, 0.f, 0.f, 0.f};
    f32x4 acc1 = {0.f, 0.f, 0.f, 0.f};

    for (int st = 0; st < NSTG; st++) {
        const int kc = kb + st * 128;
        __syncthreads();   // WAR: prior compute done before overwrite
        // stage x: 64 rows x 32 quads(4k) = 2048 quads, 8/thread, coalesced
        #pragma unroll
        for (int i = 0; i < 8; i++) {
            int j = i * 256 + tid;
            int r = j >> 5, q = j & 31;
            int k = kc + q * 4;
            uint2 pk = make_uint2(0u, 0u);
            if (k < DIN) {
                float4 v = *(const float4*)&x[(size_t)(row0 + r) * DIN + k];
                pk.x = f2bf(v.x) | (f2bf(v.y) << 16);
                pk.y = f2bf(v.z) | (f2bf(v.w) << 16);
            }
            *(uint2*)&xb[(r * 256 + q * 8) ^ ((r & 7) << 4)] = pk;
        }
        // stage w: 32 cols x 16 slots(16B) = 512 slots, 2/thread
        #pragma unroll
        for (int i = 0; i < 2; i++) {
            int s = i * 256 + tid;
            int col = s >> 4, kb16 = s & 15;
            uint4 v = *(const uint4*)&wTb[(size_t)col * KPAD + kc + kb16 * 8];
            *(uint4*)&wb[(col * 256 + kb16 * 16) ^ ((col & 7) << 4)] = v;
        }
        __syncthreads();
        // compute: 4 K-steps of 32
        #pragma unroll
        for (int ks = 0; ks < 4; ks++) {
            int koff = ks * 64 + (l >> 4) * 16;
            int sw = (l & 7) << 4;
            int arow = wid * 16 + (l & 15);
            short8 a  = *(const short8*)&xb[(arow * 256 + koff) ^ sw];
            short8 b0 = *(const short8*)&wb[((l & 15) * 256 + koff) ^ sw];
            short8 b1 = *(const short8*)&wb[(((l & 15) + 16) * 256 + koff) ^ sw];
            acc0 = __builtin_amdgcn_mfma_f32_16x16x32_bf16(a, b0, acc0, 0, 0, 0);
            acc1 = __builtin_amdgcn_mfma_f32_16x16x32_bf16(a, b1, acc1, 0, 0, 0);
        }
    }

    // epilogue: D col=l&15, row=(l>>4)*4+reg
    const int col = l & 15;
    const int rbase = row0 + wid * 16 + (l >> 4) * 4;
    #pragma unroll
    for (int reg = 0; reg < 4; reg++) {
        size_t o = ((size_t)blockIdx.y * NN + rbase + reg) * 32;
        partial[o + col]      = acc0[reg];
        partial[o + 16 + col] = acc1[reg];
    }
}

// ------- Kernel A2: h = elu(bn(sum partials + e0_b)) -------
// h aliases partial region end; each thread reads its own quad then overwrites -> safe.
__global__ void k_enc0_fin(
    const float* __restrict__ partial,
    const float* __restrict__ b, const float* __restrict__ g,
    const float* __restrict__ beta, const float* __restrict__ m,
    const float* __restrict__ v, float* __restrict__ h)
{
    int q = blockIdx.x * 256 + threadIdx.x;   // quad index over [NN*8)
    if (q >= NN * 8) return;
    int c = (q & 7) * 4;
    float4 s = make_float4(0.f, 0.f, 0.f, 0.f);
    #pragma unroll
    for (int ch = 0; ch < NCH; ch++) {
        float4 p = ((const float4*)partial)[(size_t)ch * NN * 8 + q];
        s.x += p.x; s.y += p.y; s.z += p.z; s.w += p.w;
    }
    float sc0 = g[c+0] * rsqrtf(v[c+0] + 1e-3f);
    float sc1 = g[c+1] * rsqrtf(v[c+1] + 1e-3f);
    float sc2 = g[c+2] * rsqrtf(v[c+2] + 1e-3f);
    float sc3 = g[c+3] * rsqrtf(v[c+3] + 1e-3f);
    float4 o;
    o.x = elu((s.x + b[c+0]) * sc0 + (beta[c+0] - m[c+0] * sc0));
    o.y = elu((s.y + b[c+1]) * sc1 + (beta[c+1] - m[c+1] * sc1));
    o.z = elu((s.z + b[c+2]) * sc2 + (beta[c+2] - m[c+2] * sc2));
    o.w = elu((s.w + b[c+3]) * sc3 + (beta[c+3] - m[c+3] * sc3));
    ((float4*)h)[q] = o;
}

// ------------- Kernel B: feat_x, hw1, attention scalars, init GAT1 atomics -------------
__global__ void k_enc1_prep(
    const float* __restrict__ h,
    const float* __restrict__ e1w, const float* __restrict__ e1b,
    const float* __restrict__ e1g, const float* __restrict__ e1beta,
    const float* __restrict__ e1m, const float* __restrict__ e1v,
    const float* __restrict__ g1w, const float* __restrict__ g1as,
    const float* __restrict__ g1ad,
    float* __restrict__ out_fx, float* __restrict__ hw1,
    float* __restrict__ s1src, float* __restrict__ s1dst,
    float* __restrict__ z1, float* __restrict__ acc1)
{
    int row = blockIdx.x * 256 + threadIdx.x;
    if (row >= NN) return;
    float hr[32];
    #pragma unroll
    for (int k = 0; k < 32; k++) hr[k] = h[(size_t)row * 32 + k];
    float fx[20];
    for (int c = 0; c < 20; c++) {
        float s = e1b[c];
        for (int k = 0; k < 32; k++) s += hr[k] * e1w[k * 20 + c];
        float sc = e1g[c] * rsqrtf(e1v[c] + 1e-3f);
        s = (s - e1m[c]) * sc + e1beta[c];
        fx[c] = elu(s);
        out_fx[(size_t)row * 20 + c] = fx[c];
    }
    float ss = 0.f, sd = 0.f;
    for (int c = 0; c < 64; c++) {
        float s = 0.f;
        for (int k = 0; k < 20; k++) s += fx[k] * g1w[k * 64 + c];
        hw1[(size_t)row * 64 + c] = s;
        ss += s * g1as[c];
        sd += s * g1ad[c];
        acc1[(size_t)row * 64 + c] = 0.f;
    }
    s1src[row] = ss; s1dst[row] = sd;
    z1[row] = 0.f;
}

// ------------- Kernel D: GAT1 numerator/denominator accumulate (64 lanes/edge) -------------
// softmax is shift-invariant: use exp(al) directly (logits bounded ~|3|), skip max pass.
__global__ __launch_bounds__(256) void k_gat1_acc(const int* __restrict__ ei,
    const float* __restrict__ s1src, const float* __restrict__ s1dst,
    const float* __restrict__ hw1,
    float* __restrict__ z1, float* __restrict__ acc1)
{
    int t = blockIdx.x * 256 + threadIdx.x;
    int lane = t & 63;
    int e = t >> 6;
    if (e >= ET) return;
    int s, d;
    if (e < NE) { s = ei[e]; d = ei[NE + e]; } else { s = d = e - NE; }
    float al = lrelu(s1src[s] + s1dst[d]);
    float ex = expf(al);
    if (lane == 0) atomicAdd(&z1[d], ex);
    atomicAdd(&acc1[(size_t)d * 64 + lane], ex * hw1[(size_t)s * 64 + lane]);
}

// ------------- Kernel E: normalize GAT1, BN+ReLU -> c; hw_m/hw_v + scalars; init atomics -------------
__global__ void k_gat1_norm(
    const float* __restrict__ acc1, const float* __restrict__ z1,
    const float* __restrict__ g1b,
    const float* __restrict__ bncg, const float* __restrict__ bncbeta,
    const float* __restrict__ bncm, const float* __restrict__ bncv,
    const float* __restrict__ gmw, const float* __restrict__ gmas, const float* __restrict__ gmad,
    const float* __restrict__ gvw, const float* __restrict__ gvas, const float* __restrict__ gvad,
    float* __restrict__ hwm, float* __restrict__ hwv,
    float* __restrict__ smsrc, float* __restrict__ smdst,
    float* __restrict__ svsrc, float* __restrict__ svdst,
    float* __restrict__ zm, float* __restrict__ zv,
    float* __restrict__ accm, float* __restrict__ accv)
{
    int row = blockIdx.x * 256 + threadIdx.x;
    if (row >= NN) return;
    float zi = 1.f / (z1[row] + 1e-16f);
    float c[64];
    for (int f = 0; f < 64; f++) {
        float val = acc1[(size_t)row * 64 + f] * zi + g1b[f];
        float sc = bncg[f] * rsqrtf(bncv[f] + 1e-5f);
        val = (val - bncm[f]) * sc + bncbeta[f];
        c[f] = val > 0.f ? val : 0.f;
    }
    float ssm = 0.f, sdm = 0.f, ssv = 0.f, sdv = 0.f;
    for (int o = 0; o < 8; o++) {
        float sm = 0.f, sv = 0.f;
        for (int k = 0; k < 64; k++) {
            sm += c[k] * gmw[k * 8 + o];
            sv += c[k] * gvw[k * 8 + o];
        }
        hwm[(size_t)row * 8 + o] = sm; hwv[(size_t)row * 8 + o] = sv;
        ssm += sm * gmas[o]; sdm += sm * gmad[o];
        ssv += sv * gvas[o]; sdv += sv * gvad[o];
        accm[(size_t)row * 8 + o] = 0.f; accv[(size_t)row * 8 + o] = 0.f;
    }
    smsrc[row] = ssm; smdst[row] = sdm;
    svsrc[row] = ssv; svdst[row] = sdv;
    zm[row] = 0.f;
    zv[row] = 0.f;
}

// ------------- Kernel G: mu/logvar GAT accumulate (8 lanes/edge), no max pass -------------
__global__ __launch_bounds__(256) void k_gat23_acc(const int* __restrict__ ei,
    const float* __restrict__ smsrc, const float* __restrict__ smdst,
    const float* __restrict__ svsrc, const float* __restrict__ svdst,
    const float* __restrict__ hwm, const float* __restrict__ hwv,
    float* __restrict__ zm, float* __restrict__ accm,
    float* __restrict__ zv, float* __restrict__ accv)
{
    int t = blockIdx.x * 256 + threadIdx.x;
    int lane = t & 7;
    int e = t >> 3;
    if (e >= ET) return;
    int s, d;
    if (e < NE) { s = ei[e]; d = ei[NE + e]; } else { s = d = e - NE; }
    float am = lrelu(smsrc[s] + smdst[d]);
    float exm = expf(am);
    if (lane == 0) atomicAdd(&zm[d], exm);
    atomicAdd(&accm[(size_t)d * 8 + lane], exm * hwm[(size_t)s * 8 + lane]);
    float av = lrelu(svsrc[s] + svdst[d]);
    float exv = expf(av);
    if (lane == 0) atomicAdd(&zv[d], exv);
    atomicAdd(&accv[(size_t)d * 8 + lane], exv * hwv[(size_t)s * 8 + lane]);
}

// ------------- Kernel H: mu/logvar/gnn_z/z, decoder L0, student-t q -------------
__global__ void k_final(
    const float* __restrict__ accm, const float* __restrict__ zm, const float* __restrict__ gmb,
    const float* __restrict__ accv, const float* __restrict__ zv, const float* __restrict__ gvb,
    const float* __restrict__ epsin, const float* __restrict__ fx_out,
    const float* __restrict__ d0w, const float* __restrict__ d0b,
    const float* __restrict__ d0g, const float* __restrict__ d0beta,
    const float* __restrict__ d0m, const float* __restrict__ d0v,
    const float* __restrict__ cluster,
    float* __restrict__ out_z, float* __restrict__ out_mu, float* __restrict__ out_lv,
    float* __restrict__ out_q, float* __restrict__ out_gz, float* __restrict__ dbuf)
{
    int row = blockIdx.x * 256 + threadIdx.x;
    if (row >= NN) return;
    float zvec[28];
    #pragma unroll
    for (int k = 0; k < 20; k++) zvec[k] = fx_out[(size_t)row * 20 + k];
    float zim = 1.f / (zm[row] + 1e-16f);
    float ziv = 1.f / (zv[row] + 1e-16f);
    #pragma unroll
    for (int o = 0; o < 8; o++) {
        float mu = accm[(size_t)row * 8 + o] * zim + gmb[o];
        float lv = accv[(size_t)row * 8 + o] * ziv + gvb[o];
        float gz = epsin[(size_t)row * 8 + o] * expf(lv) + mu;
        out_mu[(size_t)row * 8 + o] = mu;
        out_lv[(size_t)row * 8 + o] = lv;
        out_gz[(size_t)row * 8 + o] = gz;
        zvec[20 + o] = gz;
    }
    #pragma unroll
    for (int k = 0; k < 28; k++) out_z[(size_t)row * 28 + k] = zvec[k];
    // decoder L0: elu(bn(z @ d0_w + d0_b))
    for (int c = 0; c < 32; c++) {
        float s = d0b[c];
        for (int k = 0; k < 28; k++) s += zvec[k] * d0w[k * 32 + c];
        float sc = d0g[c] * rsqrtf(d0v[c] + 1e-3f);
        s = (s - d0m[c]) * sc + d0beta[c];
        dbuf[(size_t)row * 32 + c] = elu(s);
    }
    // student-t q
    float zz = 0.f;
    #pragma unroll
    for (int k = 0; k < 28; k++) zz += zvec[k] * zvec[k];
    float qv[15], qs = 0.f;
    for (int j = 0; j < 15; j++) {
        float cc = 0.f, zc = 0.f;
        for (int k = 0; k < 28; k++) {
            float cv = cluster[j * 28 + k];
            cc += cv * cv; zc += zvec[k] * cv;
        }
        float sq = zz + cc - 2.f * zc;
        if (sq < 0.f) sq = 0.f;
        float qb = 1.f / (1.f + sq * (1.f / 0.9f) + 1e-8f);
        qb = powf(qb, 0.95f);
        qv[j] = qb; qs += qb;
    }
    float qi = 1.f / qs;
    #pragma unroll
    for (int j = 0; j < 15; j++) out_q[(size_t)row * 15 + j] = qv[j] * qi;
}

// ------------- Kernel I: de_feat = d @ out_w + out_b -------------
#define DQ 750   // DIN/4 quads per row
__global__ __launch_bounds__(256) void k_dec_out(
    const float* __restrict__ dbuf, const float* __restrict__ ow,
    const float* __restrict__ ob, float* __restrict__ out_de)
{
    __shared__ float4 wt[32 * 64];   // [k][quad]
    __shared__ float  dt[64 * 32];   // [row][k]
    const int tid = threadIdx.x;
    const int cq0 = blockIdx.x * 64;      // quad base in output row
    const int row0 = blockIdx.y * 64;

    // load w tile: 32 k-rows x 64 quads
    #pragma unroll
    for (int i = 0; i < 8; i++) {
        int t = tid + i * 256;            // 0..2047
        int k = t >> 6, lq = t & 63;
        int gq = cq0 + lq;
        wt[t] = (gq < DQ) ? ((const float4*)ow)[(size_t)k * DQ + gq]
                          : make_float4(0.f, 0.f, 0.f, 0.f);
    }
    // load d tile: 64 rows x 32 = 512 float4
    #pragma unroll
    for (int i = 0; i < 2; i++) {
        int t = tid + i * 256;
        ((float4*)dt)[t] = ((const float4*)dbuf)[(size_t)row0 * 8 + t];
    }
    __syncthreads();

    const int qid = tid & 63;
    const int rg  = tid >> 6;             // wave-uniform row group (0..3)
    const int q   = cq0 + qid;
    const bool valid = q < DQ;

    float4 acc[16];
    #pragma unroll
    for (int r = 0; r < 16; r++) acc[r] = make_float4(0.f, 0.f, 0.f, 0.f);

    #pragma unroll
    for (int k4 = 0; k4 < 8; k4++) {
        float4 w0 = wt[(k4 * 4 + 0) * 64 + qid];
        float4 w1 = wt[(k4 * 4 + 1) * 64 + qid];
        float4 w2 = wt[(k4 * 4 + 2) * 64 + qid];
        float4 w3 = wt[(k4 * 4 + 3) * 64 + qid];
        #pragma unroll
        for (int r = 0; r < 16; r++) {
            float4 dq = *(const float4*)&dt[(rg * 16 + r) * 32 + k4 * 4]; // broadcast
            acc[r].x += dq.x * w0.x; acc[r].y += dq.x * w0.y;
            acc[r].z += dq.x * w0.z; acc[r].w += dq.x * w0.w;
            acc[r].x += dq.y * w1.x; acc[r].y += dq.y * w1.y;
            acc[r].z += dq.y * w1.z; acc[r].w += dq.y * w1.w;
            acc[r].x += dq.z * w2.x; acc[r].y += dq.z * w2.y;
            acc[r].z += dq.z * w2.z; acc[r].w += dq.z * w2.w;
            acc[r].x += dq.w * w3.x; acc[r].y += dq.w * w3.y;
            acc[r].z += dq.w * w3.z; acc[r].w += dq.w * w3.w;
        }
    }

    if (valid) {
        float4 bq = ((const float4*)ob)[q];
        #pragma unroll
        for (int r = 0; r < 16; r++) {
            float4 o;
            o.x = acc[r].x + bq.x; o.y = acc[r].y + bq.y;
            o.z = acc[r].z + bq.z; o.w = acc[r].w + bq.w;
            ((float4*)out_de)[(size_t)(row0 + rg * 16 + r) * DQ + q] = o;
        }
    }
}

extern "C" void kernel_launch(void* const* d_in, const int* in_sizes, int n_in,
                              void* d_out, int out_size, void* d_ws, size_t ws_size,
                              hipStream_t stream) {
    const float* x      = (const float*)d_in[0];
    const int*   ei     = (const int*)  d_in[1];
    const float* e0_w   = (const float*)d_in[2];
    const float* e0_b   = (const float*)d_in[3];
    const float* e0_g   = (const float*)d_in[4];
    const float* e0_be  = (const float*)d_in[5];
    const float* e0_m   = (const float*)d_in[6];
    const float* e0_v   = (const float*)d_in[7];
    const float* e1_w   = (const float*)d_in[8];
    const float* e1_b   = (const float*)d_in[9];
    const float* e1_g   = (const float*)d_in[10];
    const float* e1_be  = (const float*)d_in[11];
    const float* e1_m   = (const float*)d_in[12];
    const float* e1_v   = (const float*)d_in[13];
    const float* g1_w   = (const float*)d_in[14];
    const float* g1_as  = (const float*)d_in[15];
    const float* g1_ad  = (const float*)d_in[16];
    const float* g1_b   = (const float*)d_in[17];
    const float* bnc_g  = (const float*)d_in[18];
    const float* bnc_be = (const float*)d_in[19];
    const float* bnc_m  = (const float*)d_in[20];
    const float* bnc_v  = (const float*)d_in[21];
    const float* gm_w   = (const float*)d_in[22];
    const float* gm_as  = (const float*)d_in[23];
    const float* gm_ad  = (const float*)d_in[24];
    const float* gm_b   = (const float*)d_in[25];
    const float* gv_w   = (const float*)d_in[26];
    const float* gv_as  = (const float*)d_in[27];
    const float* gv_ad  = (const float*)d_in[28];
    const float* gv_b   = (const float*)d_in[29];
    const float* d0_w   = (const float*)d_in[30];
    const float* d0_b   = (const float*)d_in[31];
    const float* d0_g   = (const float*)d_in[32];
    const float* d0_be  = (const float*)d_in[33];
    const float* d0_m   = (const float*)d_in[34];
    const float* d0_v   = (const float*)d_in[35];
    const float* out_w  = (const float*)d_in[36];
    const float* out_b  = (const float*)d_in[37];
    const float* cluster= (const float*)d_in[38];
    const float* epsin  = (const float*)d_in[39];

    float* out = (float*)d_out;
    // output offsets (floats), return order: z, mu, logvar, de_feat, q, feat_x, gnn_z
    float* out_z  = out;
    float* out_mu = out + (size_t)NN * 28;
    float* out_lv = out + (size_t)NN * 36;
    float* out_de = out + (size_t)NN * 44;
    float* out_q  = out + (size_t)NN * 44 + (size_t)NN * DIN;
    float* out_fx = out + (size_t)NN * 59 + (size_t)NN * DIN;
    float* out_gz = out + (size_t)NN * 79 + (size_t)NN * DIN;

    float* ws = (float*)d_ws;
    const size_t n = NN;
    // enc0: partial[2][N][32] = ws[0..64N) (aliases hw1 region, used later)
    float* partial = ws;
    // phase-1 layout
    float* hw1   = ws;                 // 64N
    float* acc1  = ws + 64 * n;        // 64N
    float* hbuf  = ws + 128 * n;       // 32N (h, later reused as dbuf)
    float* s1src = ws + 160 * n;
    float* s1dst = ws + 161 * n;
    float* z1    = ws + 162 * n;
    unsigned short* wTb = (unsigned short*)(ws + 163 * n);   // 32*3072 bf16 = 48K floats
    // phase-2 layout (reuses hw1's 64N block after GAT1 is done)
    float* hwm   = ws;                 // 8N
    float* hwv   = ws + 8 * n;         // 8N
    float* smsrc = ws + 16 * n;
    float* smdst = ws + 17 * n;
    float* svsrc = ws + 18 * n;
    float* svdst = ws + 19 * n;
    float* zm    = ws + 20 * n;
    float* zv    = ws + 21 * n;
    float* accm  = ws + 24 * n;        // 8N
    float* accv  = ws + 32 * n;        // 8N
    float* dbuf  = hbuf;               // 32N

    const int NB_ROWS = (NN + 255) / 256;  // 157

    k_wprep<<<(32 * KPAD + 255) / 256, 256, 0, stream>>>(e0_w, wTb);
    dim3 enc0_grid(NN / 64, NCH);   // 625 x 2
    k_enc0<<<enc0_grid, 256, 0, stream>>>(x, wTb, partial);
    k_enc0_fin<<<(NN * 8 + 255) / 256, 256, 0, stream>>>(partial, e0_b, e0_g, e0_be,
                                                         e0_m, e0_v, hbuf);
    k_enc1_prep<<<NB_ROWS, 256, 0, stream>>>(hbuf, e1_w, e1_b, e1_g, e1_be, e1_m, e1_v,
                                             g1_w, g1_as, g1_ad,
                                             out_fx, hw1, s1src, s1dst, z1, acc1);
    k_gat1_acc<<<(ET * 64) / 256, 256, 0, stream>>>(ei, s1src, s1dst, hw1, z1, acc1);
    k_gat1_norm<<<NB_ROWS, 256, 0, stream>>>(acc1, z1, g1_b, bnc_g, bnc_be, bnc_m, bnc_v,
                                             gm_w, gm_as, gm_ad, gv_w, gv_as, gv_ad,
                                             hwm, hwv, smsrc, smdst, svsrc, svdst,
                                             zm, zv, accm, accv);
    k_gat23_acc<<<(ET * 8) / 256, 256, 0, stream>>>(ei, smsrc, smdst, svsrc, svdst,
                                                    hwm, hwv, zm, accm, zv, accv);
    k_final<<<NB_ROWS, 256, 0, stream>>>(accm, zm, gm_b, accv, zv, gv_b, epsin, out_fx,
                                         d0_w, d0_b, d0_g, d0_be, d0_m, d0_v, cluster,
                                         out_z, out_mu, out_lv, out_q, out_gz, dbuf);
    dim3 dec_grid((DQ + 63) / 64, NN / 64);
    k_dec_out<<<dec_grid, 256, 0, stream>>>(dbuf, out_w, out_b, out_de);
}

// Round 13
// 658.118 us; speedup vs baseline: 1.4412x; 1.1114x over previous
//
#include <hip/hip_runtime.h>
#include <cfloat>
#include <cmath>

#define NN 40000
#define DIN 3000
#define NE 640000
#define ET (NE + NN)   // edges incl. self-loops = 680000

#define NCH 2         // split-K chunks for enc0
#define KPAD 3072     // padded K (2 x 1536)
#define KCHUNK 1536   // K per chunk
#define NSTG 12       // 128-k stages per chunk
#define CPAD 3072     // padded col count for owTb

typedef __attribute__((ext_vector_type(8))) short short8;
typedef __attribute__((ext_vector_type(4))) float f32x4;

__device__ __forceinline__ float lrelu(float x) { return x >= 0.f ? x : 0.2f * x; }
__device__ __forceinline__ float elu(float x)   { return x > 0.f ? x : expm1f(x); }
__device__ __forceinline__ unsigned f2bf(float f) {
    unsigned u = __float_as_uint(f);
    return (u + 0x7FFFu + ((u >> 16) & 1u)) >> 16;   // RNE fp32->bf16
}

// ================= CSR build (dst-sorted edge list, built per call) =================
__global__ void k_zero(int* __restrict__ p, int ncnt) {
    int i = blockIdx.x * 256 + threadIdx.x;
    if (i < ncnt) p[i] = 0;
}

__global__ void k_deg(const int* __restrict__ ei, int* __restrict__ deg) {
    int e = blockIdx.x * 256 + threadIdx.x;
    if (e >= ET) return;
    int d = (e < NE) ? ei[NE + e] : e - NE;
    atomicAdd(&deg[d], 1);
}

// single-block exclusive scan of deg[NN] -> start[NN]
__global__ __launch_bounds__(1024) void k_scan(const int* __restrict__ deg,
                                               int* __restrict__ start) {
    __shared__ int sums[1024];
    const int t = threadIdx.x;
    const int base = t * 40;                 // 1024*40 = 40960 >= NN
    int s = 0;
    for (int i = 0; i < 40; i++) {
        int idx = base + i;
        if (idx < NN) s += deg[idx];
    }
    sums[t] = s; __syncthreads();
    for (int off = 1; off < 1024; off <<= 1) {
        int v = sums[t];
        int add = (t >= off) ? sums[t - off] : 0;
        __syncthreads();
        sums[t] = v + add;
        __syncthreads();
    }
    int run = (t > 0) ? sums[t - 1] : 0;
    for (int i = 0; i < 40; i++) {
        int idx = base + i;
        if (idx < NN) { start[idx] = run; run += deg[idx]; }
    }
}

__global__ void k_fill(const int* __restrict__ ei, const int* __restrict__ start,
                       int* __restrict__ cnt, int* __restrict__ srcs) {
    int e = blockIdx.x * 256 + threadIdx.x;
    if (e >= ET) return;
    int s, d;
    if (e < NE) { s = ei[e]; d = ei[NE + e]; } else { s = d = e - NE; }
    int pos = start[d] + atomicAdd(&cnt[d], 1);
    srcs[pos] = s;
}

// ------- Kernel A0: wTb[32][3072] bf16 = transpose(e0_w[3000][32]), zero-padded -------
__global__ void k_wprep(const float* __restrict__ w, unsigned short* __restrict__ wTb)
{
    int id = blockIdx.x * 256 + threadIdx.x;
    if (id >= 32 * KPAD) return;
    int c = id / KPAD, k = id - c * KPAD;
    float v = (k < DIN) ? w[(size_t)k * 32 + c] : 0.f;
    wTb[id] = (unsigned short)f2bf(v);
}

// ------- owTb[3072][32] bf16 = transpose(out_w[32][3000]), zero-padded cols -------
__global__ void k_owprep(const float* __restrict__ ow, unsigned short* __restrict__ owTb)
{
    int id = blockIdx.x * 256 + threadIdx.x;
    if (id >= CPAD * 32) return;
    int col = id >> 5, k = id & 31;
    owTb[id] = (col < DIN) ? (unsigned short)f2bf(ow[(size_t)k * DIN + col]) : 0;
}

// ---------------- Kernel A: partial = x @ e0_w via MFMA bf16 ----------------
__global__ __launch_bounds__(256) void k_enc0(
    const float* __restrict__ x, const unsigned short* __restrict__ wTb,
    float* __restrict__ partial)   // [NCH][NN][32]
{
    __shared__ __align__(16) char xb[64 * 256];   // 16 KB: bf16 [64 r][128 k] swz
    __shared__ __align__(16) char wb[32 * 256];   //  8 KB: bf16 [32 c][128 k] swz
    const int tid = threadIdx.x;
    const int wid = tid >> 6;
    const int l = tid & 63;
    const int row0 = blockIdx.x * 64;
    const int kb = blockIdx.y * KCHUNK;

    f32x4 acc0 = {0.f, 0.f, 0.f, 0.f};
    f32x4 acc1 = {0.f, 0.f, 0.f, 0.f};

    for (int st = 0; st < NSTG; st++) {
        const int kc = kb + st * 128;
        __syncthreads();
        #pragma unroll
        for (int i = 0; i < 8; i++) {
            int j = i * 256 + tid;
            int r = j >> 5, q = j & 31;
            int k = kc + q * 4;
            uint2 pk = make_uint2(0u, 0u);
            if (k < DIN) {
                float4 v = *(const float4*)&x[(size_t)(row0 + r) * DIN + k];
                pk.x = f2bf(v.x) | (f2bf(v.y) << 16);
                pk.y = f2bf(v.z) | (f2bf(v.w) << 16);
            }
            *(uint2*)&xb[(r * 256 + q * 8) ^ ((r & 7) << 4)] = pk;
        }
        #pragma unroll
        for (int i = 0; i < 2; i++) {
            int s = i * 256 + tid;
            int col = s >> 4, kb16 = s & 15;
            uint4 v = *(const uint4*)&wTb[(size_t)col * KPAD + kc + kb16 * 8];
            *(uint4*)&wb[(col * 256 + kb16 * 16) ^ ((col & 7) << 4)] = v;
        }
        __syncthreads();
        #pragma unroll
        for (int ks = 0; ks < 4; ks++) {
            int koff = ks * 64 + (l >> 4) * 16;
            int sw = (l & 7) << 4;
            int arow = wid * 16 + (l & 15);
            short8 a  = *(const short8*)&xb[(arow * 256 + koff) ^ sw];
            short8 b0 = *(const short8*)&wb[((l & 15) * 256 + koff) ^ sw];
            short8 b1 = *(const short8*)&wb[(((l & 15) + 16) * 256 + koff) ^ sw];
            acc0 = __builtin_amdgcn_mfma_f32_16x16x32_bf16(a, b0, acc0, 0, 0, 0);
            acc1 = __builtin_amdgcn_mfma_f32_16x16x32_bf16(a, b1, acc1, 0, 0, 0);
        }
    }

    const int col = l & 15;
    const int rbase = row0 + wid * 16 + (l >> 4) * 4;
    #pragma unroll
    for (int reg = 0; reg < 4; reg++) {
        size_t o = ((size_t)blockIdx.y * NN + rbase + reg) * 32;
        partial[o + col]      = acc0[reg];
        partial[o + 16 + col] = acc1[reg];
    }
}

// ------- Kernel A2: h = elu(bn(sum partials + e0_b)) -------
__global__ void k_enc0_fin(
    const float* __restrict__ partial,
    const float* __restrict__ b, const float* __restrict__ g,
    const float* __restrict__ beta, const float* __restrict__ m,
    const float* __restrict__ v, float* __restrict__ h)
{
    int q = blockIdx.x * 256 + threadIdx.x;   // quad index over [NN*8)
    if (q >= NN * 8) return;
    int c = (q & 7) * 4;
    float4 s = make_float4(0.f, 0.f, 0.f, 0.f);
    #pragma unroll
    for (int ch = 0; ch < NCH; ch++) {
        float4 p = ((const float4*)partial)[(size_t)ch * NN * 8 + q];
        s.x += p.x; s.y += p.y; s.z += p.z; s.w += p.w;
    }
    float sc0 = g[c+0] * rsqrtf(v[c+0] + 1e-3f);
    float sc1 = g[c+1] * rsqrtf(v[c+1] + 1e-3f);
    float sc2 = g[c+2] * rsqrtf(v[c+2] + 1e-3f);
    float sc3 = g[c+3] * rsqrtf(v[c+3] + 1e-3f);
    float4 o;
    o.x = elu((s.x + b[c+0]) * sc0 + (beta[c+0] - m[c+0] * sc0));
    o.y = elu((s.y + b[c+1]) * sc1 + (beta[c+1] - m[c+1] * sc1));
    o.z = elu((s.z + b[c+2]) * sc2 + (beta[c+2] - m[c+2] * sc2));
    o.w = elu((s.w + b[c+3]) * sc3 + (beta[c+3] - m[c+3] * sc3));
    ((float4*)h)[q] = o;
}

// ------------- Kernel B: feat_x, hw1, attention scalars -------------
__global__ void k_enc1_prep(
    const float* __restrict__ h,
    const float* __restrict__ e1w, const float* __restrict__ e1b,
    const float* __restrict__ e1g, const float* __restrict__ e1beta,
    const float* __restrict__ e1m, const float* __restrict__ e1v,
    const float* __restrict__ g1w, const float* __restrict__ g1as,
    const float* __restrict__ g1ad,
    float* __restrict__ out_fx, float* __restrict__ hw1,
    float* __restrict__ s1src, float* __restrict__ s1dst)
{
    int row = blockIdx.x * 256 + threadIdx.x;
    if (row >= NN) return;
    float hr[32];
    #pragma unroll
    for (int k = 0; k < 32; k++) hr[k] = h[(size_t)row * 32 + k];
    float fx[20];
    for (int c = 0; c < 20; c++) {
        float s = e1b[c];
        for (int k = 0; k < 32; k++) s += hr[k] * e1w[k * 20 + c];
        float sc = e1g[c] * rsqrtf(e1v[c] + 1e-3f);
        s = (s - e1m[c]) * sc + e1beta[c];
        fx[c] = elu(s);
        out_fx[(size_t)row * 20 + c] = fx[c];
    }
    float ss = 0.f, sd = 0.f;
    for (int c = 0; c < 64; c++) {
        float s = 0.f;
        for (int k = 0; k < 20; k++) s += fx[k] * g1w[k * 64 + c];
        hw1[(size_t)row * 64 + c] = s;
        ss += s * g1as[c];
        sd += s * g1ad[c];
    }
    s1src[row] = ss; s1dst[row] = sd;
}

// ------------- GAT1 gather: one wave per dst, 64 lanes = features, NO atomics -------------
__global__ __launch_bounds__(256) void k_gat1_gather(
    const int* __restrict__ start, const int* __restrict__ deg,
    const int* __restrict__ srcs,
    const float* __restrict__ s1src, const float* __restrict__ s1dst,
    const float* __restrict__ hw1,
    float* __restrict__ z1, float* __restrict__ acc1)
{
    int d = (blockIdx.x * 256 + threadIdx.x) >> 6;
    int l = threadIdx.x & 63;
    if (d >= NN) return;
    int j0 = start[d], j1 = j0 + deg[d];
    float sd = s1dst[d];
    float acc = 0.f, z = 0.f;
    for (int j = j0; j < j1; j++) {
        int s = srcs[j];                       // wave-uniform
        float ex = expf(lrelu(s1src[s] + sd)); // softmax shift-invariant, no max pass
        z += ex;
        acc += ex * hw1[(size_t)s * 64 + l];   // coalesced 256B row
    }
    acc1[(size_t)d * 64 + l] = acc;
    if (l == 0) z1[d] = z;
}

// ------------- Kernel E: normalize GAT1, BN+ReLU -> c; hw_m/hw_v + scalars -------------
__global__ void k_gat1_norm(
    const float* __restrict__ acc1, const float* __restrict__ z1,
    const float* __restrict__ g1b,
    const float* __restrict__ bncg, const float* __restrict__ bncbeta,
    const float* __restrict__ bncm, const float* __restrict__ bncv,
    const float* __restrict__ gmw, const float* __restrict__ gmas, const float* __restrict__ gmad,
    const float* __restrict__ gvw, const float* __restrict__ gvas, const float* __restrict__ gvad,
    float* __restrict__ hwm, float* __restrict__ hwv,
    float* __restrict__ smsrc, float* __restrict__ smdst,
    float* __restrict__ svsrc, float* __restrict__ svdst)
{
    int row = blockIdx.x * 256 + threadIdx.x;
    if (row >= NN) return;
    float zi = 1.f / (z1[row] + 1e-16f);
    float c[64];
    for (int f = 0; f < 64; f++) {
        float val = acc1[(size_t)row * 64 + f] * zi + g1b[f];
        float sc = bncg[f] * rsqrtf(bncv[f] + 1e-5f);
        val = (val - bncm[f]) * sc + bncbeta[f];
        c[f] = val > 0.f ? val : 0.f;
    }
    float ssm = 0.f, sdm = 0.f, ssv = 0.f, sdv = 0.f;
    for (int o = 0; o < 8; o++) {
        float sm = 0.f, sv = 0.f;
        for (int k = 0; k < 64; k++) {
            sm += c[k] * gmw[k * 8 + o];
            sv += c[k] * gvw[k * 8 + o];
        }
        hwm[(size_t)row * 8 + o] = sm; hwv[(size_t)row * 8 + o] = sv;
        ssm += sm * gmas[o]; sdm += sm * gmad[o];
        ssv += sv * gvas[o]; sdv += sv * gvad[o];
    }
    smsrc[row] = ssm; smdst[row] = sdm;
    svsrc[row] = ssv; svdst[row] = sdv;
}

// ------------- GAT2/3 gather: one wave per dst; lanes = 16 feat (8m+8v) x 4 edge-groups -------------
__global__ __launch_bounds__(256) void k_gat23_gather(
    const int* __restrict__ start, const int* __restrict__ deg,
    const int* __restrict__ srcs,
    const float* __restrict__ smsrc, const float* __restrict__ smdst,
    const float* __restrict__ svsrc, const float* __restrict__ svdst,
    const float* __restrict__ hwm, const float* __restrict__ hwv,
    float* __restrict__ zm, float* __restrict__ accm,
    float* __restrict__ zv, float* __restrict__ accv)
{
    int d = (blockIdx.x * 256 + threadIdx.x) >> 6;
    int l = threadIdx.x & 63;
    if (d >= NN) return;
    const int eg = l >> 4;
    const bool isv = (l & 15) >= 8;
    const int f = l & 7;
    int j0 = start[d], n = deg[d];
    float sdst = isv ? svdst[d] : smdst[d];
    float acc = 0.f, z = 0.f;
    for (int j = eg; j < n; j += 4) {
        int s = srcs[j0 + j];
        float a = (isv ? svsrc[s] : smsrc[s]) + sdst;
        float ex = expf(lrelu(a));
        z += ex;
        float hv = isv ? hwv[(size_t)s * 8 + f] : hwm[(size_t)s * 8 + f];
        acc += ex * hv;
    }
    acc += __shfl_xor(acc, 16); acc += __shfl_xor(acc, 32);
    z   += __shfl_xor(z, 16);   z   += __shfl_xor(z, 32);
    if (l < 16) {
        if (!isv) { accm[(size_t)d * 8 + f] = acc; if (f == 0) zm[d] = z; }
        else      { accv[(size_t)d * 8 + f] = acc; if (f == 0) zv[d] = z; }
    }
}

// ------------- Kernel H: mu/logvar/gnn_z/z, decoder L0, student-t q -------------
__global__ void k_final(
    const float* __restrict__ accm, const float* __restrict__ zm, const float* __restrict__ gmb,
    const float* __restrict__ accv, const float* __restrict__ zv, const float* __restrict__ gvb,
    const float* __restrict__ epsin, const float* __restrict__ fx_out,
    const float* __restrict__ d0w, const float* __restrict__ d0b,
    const float* __restrict__ d0g, const float* __restrict__ d0beta,
    const float* __restrict__ d0m, const float* __restrict__ d0v,
    const float* __restrict__ cluster,
    float* __restrict__ out_z, float* __restrict__ out_mu, float* __restrict__ out_lv,
    float* __restrict__ out_q, float* __restrict__ out_gz, float* __restrict__ dbuf)
{
    int row = blockIdx.x * 256 + threadIdx.x;
    if (row >= NN) return;
    float zvec[28];
    #pragma unroll
    for (int k = 0; k < 20; k++) zvec[k] = fx_out[(size_t)row * 20 + k];
    float zim = 1.f / (zm[row] + 1e-16f);
    float ziv = 1.f / (zv[row] + 1e-16f);
    #pragma unroll
    for (int o = 0; o < 8; o++) {
        float mu = accm[(size_t)row * 8 + o] * zim + gmb[o];
        float lv = accv[(size_t)row * 8 + o] * ziv + gvb[o];
        float gz = epsin[(size_t)row * 8 + o] * expf(lv) + mu;
        out_mu[(size_t)row * 8 + o] = mu;
        out_lv[(size_t)row * 8 + o] = lv;
        out_gz[(size_t)row * 8 + o] = gz;
        zvec[20 + o] = gz;
    }
    #pragma unroll
    for (int k = 0; k < 28; k++) out_z[(size_t)row * 28 + k] = zvec[k];
    for (int c = 0; c < 32; c++) {
        float s = d0b[c];
        for (int k = 0; k < 28; k++) s += zvec[k] * d0w[k * 32 + c];
        float sc = d0g[c] * rsqrtf(d0v[c] + 1e-3f);
        s = (s - d0m[c]) * sc + d0beta[c];
        dbuf[(size_t)row * 32 + c] = elu(s);
    }
    float zz = 0.f;
    #pragma unroll
    for (int k = 0; k < 28; k++) zz += zvec[k] * zvec[k];
    float qv[15], qs = 0.f;
    for (int j = 0; j < 15; j++) {
        float cc = 0.f, zc = 0.f;
        for (int k = 0; k < 28; k++) {
            float cv = cluster[j * 28 + k];
            cc += cv * cv; zc += zvec[k] * cv;
        }
        float sq = zz + cc - 2.f * zc;
        if (sq < 0.f) sq = 0.f;
        float qb = 1.f / (1.f + sq * (1.f / 0.9f) + 1e-8f);
        qb = powf(qb, 0.95f);
        qv[j] = qb; qs += qb;
    }
    float qi = 1.f / qs;
    #pragma unroll
    for (int j = 0; j < 15; j++) out_q[(size_t)row * 15 + j] = qv[j] * qi;
}

// ------------- Kernel I: de_feat = d @ out_w + out_b via MFMA bf16 -------------
// Block 256 = 4 waves; tile 64 rows x 128 cols; K=32 = one mfma per 16x16 tile.
// A,B staged in frag-ordered LDS (contiguous 1KB/wave reads, conflict-free).
__global__ __launch_bounds__(256) void k_dec_out(
    const float* __restrict__ dbuf, const unsigned short* __restrict__ owTb,
    const float* __restrict__ ob, float* __restrict__ out_de)
{
    __shared__ __align__(16) char ab[4 * 1024];    // A frags, 4 row-groups
    __shared__ __align__(16) char bb[8 * 1024];    // B frags, 8 col-tiles
    const int tid = threadIdx.x, wid = tid >> 6, l = tid & 63;
    const int row0 = blockIdx.y * 64;
    const int c0 = blockIdx.x * 128;

    // stage A: dbuf[64][32] fp32 -> bf16 frag order
    #pragma unroll
    for (int i = 0; i < 2; i++) {
        int j = i * 256 + tid;          // 0..511 quads
        int r = j >> 3, kq = j & 7;
        float4 v = *(const float4*)&dbuf[(size_t)(row0 + r) * 32 + kq * 4];
        uint2 pk;
        pk.x = f2bf(v.x) | (f2bf(v.y) << 16);
        pk.y = f2bf(v.z) | (f2bf(v.w) << 16);
        int g = r >> 4, fl = (r & 15) | ((kq >> 1) << 4);
        *(uint2*)&ab[g * 1024 + fl * 16 + (kq & 1) * 8] = pk;
    }
    // stage B: 8 col-tiles x 64 lane-slots of 16B from owTb[col][32]
    #pragma unroll
    for (int i = 0; i < 2; i++) {
        int sid = i * 256 + tid;
        int ct = sid >> 6, bl = sid & 63;
        int col = c0 + ct * 16 + (bl & 15);
        uint4 v = *(const uint4*)&owTb[(size_t)col * 32 + (bl >> 4) * 8];
        *(uint4*)&bb[ct * 1024 + bl * 16] = v;
    }
    __syncthreads();

    short8 a = *(const short8*)&ab[wid * 1024 + l * 16];
    const int rw = row0 + wid * 16 + (l >> 4) * 4;
    #pragma unroll
    for (int ct = 0; ct < 8; ct++) {
        short8 b = *(const short8*)&bb[ct * 1024 + l * 16];
        f32x4 acc = {0.f, 0.f, 0.f, 0.f};
        acc = __builtin_amdgcn_mfma_f32_16x16x32_bf16(a, b, acc, 0, 0, 0);
        int col = c0 + ct * 16 + (l & 15);
        if (col < DIN) {
            float bias = ob[col];
            #pragma unroll
            for (int reg = 0; reg < 4; reg++)
                out_de[(size_t)(rw + reg) * DIN + col] = acc[reg] + bias;
        }
    }
}

extern "C" void kernel_launch(void* const* d_in, const int* in_sizes, int n_in,
                              void* d_out, int out_size, void* d_ws, size_t ws_size,
                              hipStream_t stream) {
    const float* x      = (const float*)d_in[0];
    const int*   ei     = (const int*)  d_in[1];
    const float* e0_w   = (const float*)d_in[2];
    const float* e0_b   = (const float*)d_in[3];
    const float* e0_g   = (const float*)d_in[4];
    const float* e0_be  = (const float*)d_in[5];
    const float* e0_m   = (const float*)d_in[6];
    const float* e0_v   = (const float*)d_in[7];
    const float* e1_w   = (const float*)d_in[8];
    const float* e1_b   = (const float*)d_in[9];
    const float* e1_g   = (const float*)d_in[10];
    const float* e1_be  = (const float*)d_in[11];
    const float* e1_m   = (const float*)d_in[12];
    const float* e1_v   = (const float*)d_in[13];
    const float* g1_w   = (const float*)d_in[14];
    const float* g1_as  = (const float*)d_in[15];
    const float* g1_ad  = (const float*)d_in[16];
    const float* g1_b   = (const float*)d_in[17];
    const float* bnc_g  = (const float*)d_in[18];
    const float* bnc_be = (const float*)d_in[19];
    const float* bnc_m  = (const float*)d_in[20];
    const float* bnc_v  = (const float*)d_in[21];
    const float* gm_w   = (const float*)d_in[22];
    const float* gm_as  = (const float*)d_in[23];
    const float* gm_ad  = (const float*)d_in[24];
    const float* gm_b   = (const float*)d_in[25];
    const float* gv_w   = (const float*)d_in[26];
    const float* gv_as  = (const float*)d_in[27];
    const float* gv_ad  = (const float*)d_in[28];
    const float* gv_b   = (const float*)d_in[29];
    const float* d0_w   = (const float*)d_in[30];
    const float* d0_b   = (const float*)d_in[31];
    const float* d0_g   = (const float*)d_in[32];
    const float* d0_be  = (const float*)d_in[33];
    const float* d0_m   = (const float*)d_in[34];
    const float* d0_v   = (const float*)d_in[35];
    const float* out_w  = (const float*)d_in[36];
    const float* out_b  = (const float*)d_in[37];
    const float* cluster= (const float*)d_in[38];
    const float* epsin  = (const float*)d_in[39];

    float* out = (float*)d_out;
    // output offsets (floats), return order: z, mu, logvar, de_feat, q, feat_x, gnn_z
    float* out_z  = out;
    float* out_mu = out + (size_t)NN * 28;
    float* out_lv = out + (size_t)NN * 36;
    float* out_de = out + (size_t)NN * 44;
    float* out_q  = out + (size_t)NN * 44 + (size_t)NN * DIN;
    float* out_fx = out + (size_t)NN * 59 + (size_t)NN * DIN;
    float* out_gz = out + (size_t)NN * 79 + (size_t)NN * DIN;

    float* ws = (float*)d_ws;
    const size_t n = NN;
    // enc0: partial[2][N][32] = ws[0..64N) (aliases hw1 region, used later)
    float* partial = ws;
    // phase-1 layout
    float* hw1   = ws;                 // 64N
    float* acc1  = ws + 64 * n;        // 64N
    float* hbuf  = ws + 128 * n;       // 32N (h, later reused as dbuf)
    float* s1src = ws + 160 * n;
    float* s1dst = ws + 161 * n;
    float* z1    = ws + 162 * n;
    unsigned short* wTb  = (unsigned short*)(ws + 163 * n);            // 32*3072 bf16
    unsigned short* owTb = (unsigned short*)(ws + 163 * n + 49152);    // 3072*32 bf16
    // phase-2 layout (reuses hw1's 64N block after GAT1 is done)
    float* hwm   = ws;                 // 8N
    float* hwv   = ws + 8 * n;         // 8N
    float* smsrc = ws + 16 * n;
    float* smdst = ws + 17 * n;
    float* svsrc = ws + 18 * n;
    float* svdst = ws + 19 * n;
    float* zm    = ws + 20 * n;
    float* zv    = ws + 21 * n;
    float* accm  = ws + 24 * n;        // 8N
    float* accv  = ws + 32 * n;        // 8N
    float* dbuf  = hbuf;               // 32N

    // CSR scratch lives in the de_feat output region (overwritten last by k_dec_out)
    int* srcs  = (int*)out_de;         // ET
    int* deg   = srcs + ET;            // NN
    int* cnt   = deg + NN;             // NN
    int* start = cnt + NN;             // NN

    const int NB_ROWS = (NN + 255) / 256;  // 157
    const int NB_E    = (ET + 255) / 256;

    // CSR build
    k_zero<<<(2 * NN + 255) / 256, 256, 0, stream>>>(deg, 2 * NN);   // deg + cnt
    k_deg<<<NB_E, 256, 0, stream>>>(ei, deg);
    k_scan<<<1, 1024, 0, stream>>>(deg, start);
    k_fill<<<NB_E, 256, 0, stream>>>(ei, start, cnt, srcs);

    // weight preps
    k_wprep<<<(32 * KPAD + 255) / 256, 256, 0, stream>>>(e0_w, wTb);
    k_owprep<<<(CPAD * 32 + 255) / 256, 256, 0, stream>>>(out_w, owTb);

    // encoder
    dim3 enc0_grid(NN / 64, NCH);   // 625 x 2
    k_enc0<<<enc0_grid, 256, 0, stream>>>(x, wTb, partial);
    k_enc0_fin<<<(NN * 8 + 255) / 256, 256, 0, stream>>>(partial, e0_b, e0_g, e0_be,
                                                         e0_m, e0_v, hbuf);
    k_enc1_prep<<<NB_ROWS, 256, 0, stream>>>(hbuf, e1_w, e1_b, e1_g, e1_be, e1_m, e1_v,
                                             g1_w, g1_as, g1_ad,
                                             out_fx, hw1, s1src, s1dst);
    // GAT1 (gather, no atomics)
    k_gat1_gather<<<(NN * 64 + 255) / 256, 256, 0, stream>>>(start, deg, srcs,
                                                             s1src, s1dst, hw1, z1, acc1);
    k_gat1_norm<<<NB_ROWS, 256, 0, stream>>>(acc1, z1, g1_b, bnc_g, bnc_be, bnc_m, bnc_v,
                                             gm_w, gm_as, gm_ad, gv_w, gv_as, gv_ad,
                                             hwm, hwv, smsrc, smdst, svsrc, svdst);
    // GAT mu/logvar (gather)
    k_gat23_gather<<<(NN * 64 + 255) / 256, 256, 0, stream>>>(start, deg, srcs,
                                                              smsrc, smdst, svsrc, svdst,
                                                              hwm, hwv, zm, accm, zv, accv);
    k_final<<<NB_ROWS, 256, 0, stream>>>(accm, zm, gm_b, accv, zv, gv_b, epsin, out_fx,
                                         d0_w, d0_b, d0_g, d0_be, d0_m, d0_v, cluster,
                                         out_z, out_mu, out_lv, out_q, out_gz, dbuf);
    // decoder out (MFMA)
    dim3 dec_grid((CPAD + 127) / 128, NN / 64);   // 24 x 625
    k_dec_out<<<dec_grid, 256, 0, stream>>>(dbuf, owTb, out_b, out_de);
}

// Round 14
// 633.859 us; speedup vs baseline: 1.4964x; 1.0383x over previous
//
#include <hip/hip_runtime.h>
#include <cfloat>
#include <cmath>

#define NN 40000
#define DIN 3000
#define NE 640000
#define ET (NE + NN)   // edges incl. self-loops = 680000

#define NCH 2         // split-K chunks for enc0
#define KPAD 3072     // padded K (2 x 1536)
#define KCHUNK 1536   // K per chunk
#define NSTG 12       // 128-k stages per chunk
#define NCT 192       // B-frag col tiles (192*16 = 3072 >= DIN)

typedef __attribute__((ext_vector_type(8))) short short8;
typedef __attribute__((ext_vector_type(4))) float f32x4;

__device__ __forceinline__ float lrelu(float x) { return x >= 0.f ? x : 0.2f * x; }
__device__ __forceinline__ float elu(float x)   { return x > 0.f ? x : expm1f(x); }
__device__ __forceinline__ unsigned f2bf(float f) {
    unsigned u = __float_as_uint(f);
    return (u + 0x7FFFu + ((u >> 16) & 1u)) >> 16;   // RNE fp32->bf16
}

// ================= CSR build (dst-sorted edge list, built per call) =================
__global__ void k_zero(int* __restrict__ p, int ncnt) {
    int i = blockIdx.x * 256 + threadIdx.x;
    if (i < ncnt) p[i] = 0;
}

__global__ void k_deg(const int* __restrict__ ei, int* __restrict__ deg) {
    int e = blockIdx.x * 256 + threadIdx.x;
    if (e >= ET) return;
    int d = (e < NE) ? ei[NE + e] : e - NE;
    atomicAdd(&deg[d], 1);
}

// single-block exclusive scan of deg[NN] -> start[NN]
__global__ __launch_bounds__(1024) void k_scan(const int* __restrict__ deg,
                                               int* __restrict__ start) {
    __shared__ int sums[1024];
    const int t = threadIdx.x;
    const int base = t * 40;                 // 1024*40 = 40960 >= NN
    int s = 0;
    for (int i = 0; i < 40; i++) {
        int idx = base + i;
        if (idx < NN) s += deg[idx];
    }
    sums[t] = s; __syncthreads();
    for (int off = 1; off < 1024; off <<= 1) {
        int v = sums[t];
        int add = (t >= off) ? sums[t - off] : 0;
        __syncthreads();
        sums[t] = v + add;
        __syncthreads();
    }
    int run = (t > 0) ? sums[t - 1] : 0;
    for (int i = 0; i < 40; i++) {
        int idx = base + i;
        if (idx < NN) { start[idx] = run; run += deg[idx]; }
    }
}

__global__ void k_fill(const int* __restrict__ ei, const int* __restrict__ start,
                       int* __restrict__ cnt, int* __restrict__ srcs) {
    int e = blockIdx.x * 256 + threadIdx.x;
    if (e >= ET) return;
    int s, d;
    if (e < NE) { s = ei[e]; d = ei[NE + e]; } else { s = d = e - NE; }
    int pos = start[d] + atomicAdd(&cnt[d], 1);
    srcs[pos] = s;
}

// ------- weight prep: wTb[32][3072] bf16 (enc0 B) + bfragb[192 ct][64 lanes][8] (dec B-frags) -------
__global__ void k_prep_w(const float* __restrict__ w, const float* __restrict__ ow,
                         unsigned short* __restrict__ wTb,
                         unsigned short* __restrict__ bfragb)
{
    int id = blockIdx.x * 256 + threadIdx.x;
    if (id < 32 * KPAD) {
        int c = id / KPAD, k = id - c * KPAD;
        float v = (k < DIN) ? w[(size_t)k * 32 + c] : 0.f;
        wTb[id] = (unsigned short)f2bf(v);
    } else {
        int t = id - 32 * KPAD;
        if (t < NCT * 64) {
            int ct = t >> 6, l = t & 63;
            int col = ct * 16 + (l & 15);
            int k0 = (l >> 4) * 8;
            uint4 p = make_uint4(0u, 0u, 0u, 0u);
            if (col < DIN) {
                unsigned v[8];
                #pragma unroll
                for (int j = 0; j < 8; j++)
                    v[j] = f2bf(ow[(size_t)(k0 + j) * DIN + col]);
                p.x = v[0] | (v[1] << 16); p.y = v[2] | (v[3] << 16);
                p.z = v[4] | (v[5] << 16); p.w = v[6] | (v[7] << 16);
            }
            *(uint4*)&bfragb[((size_t)ct * 64 + l) * 8] = p;
        }
    }
}

// ---------------- Kernel A: partial = x @ e0_w via MFMA bf16 ----------------
__global__ __launch_bounds__(256) void k_enc0(
    const float* __restrict__ x, const unsigned short* __restrict__ wTb,
    float* __restrict__ partial)   // [NCH][NN][32]
{
    __shared__ __align__(16) char xb[64 * 256];   // 16 KB: bf16 [64 r][128 k] swz
    __shared__ __align__(16) char wb[32 * 256];   //  8 KB: bf16 [32 c][128 k] swz
    const int tid = threadIdx.x;
    const int wid = tid >> 6;
    const int l = tid & 63;
    const int row0 = blockIdx.x * 64;
    const int kb = blockIdx.y * KCHUNK;

    f32x4 acc0 = {0.f, 0.f, 0.f, 0.f};
    f32x4 acc1 = {0.f, 0.f, 0.f, 0.f};

    for (int st = 0; st < NSTG; st++) {
        const int kc = kb + st * 128;
        __syncthreads();
        #pragma unroll
        for (int i = 0; i < 8; i++) {
            int j = i * 256 + tid;
            int r = j >> 5, q = j & 31;
            int k = kc + q * 4;
            uint2 pk = make_uint2(0u, 0u);
            if (k < DIN) {
                float4 v = *(const float4*)&x[(size_t)(row0 + r) * DIN + k];
                pk.x = f2bf(v.x) | (f2bf(v.y) << 16);
                pk.y = f2bf(v.z) | (f2bf(v.w) << 16);
            }
            *(uint2*)&xb[(r * 256 + q * 8) ^ ((r & 7) << 4)] = pk;
        }
        #pragma unroll
        for (int i = 0; i < 2; i++) {
            int s = i * 256 + tid;
            int col = s >> 4, kb16 = s & 15;
            uint4 v = *(const uint4*)&wTb[(size_t)col * KPAD + kc + kb16 * 8];
            *(uint4*)&wb[(col * 256 + kb16 * 16) ^ ((col & 7) << 4)] = v;
        }
        __syncthreads();
        #pragma unroll
        for (int ks = 0; ks < 4; ks++) {
            int koff = ks * 64 + (l >> 4) * 16;
            int sw = (l & 7) << 4;
            int arow = wid * 16 + (l & 15);
            short8 a  = *(const short8*)&xb[(arow * 256 + koff) ^ sw];
            short8 b0 = *(const short8*)&wb[((l & 15) * 256 + koff) ^ sw];
            short8 b1 = *(const short8*)&wb[(((l & 15) + 16) * 256 + koff) ^ sw];
            acc0 = __builtin_amdgcn_mfma_f32_16x16x32_bf16(a, b0, acc0, 0, 0, 0);
            acc1 = __builtin_amdgcn_mfma_f32_16x16x32_bf16(a, b1, acc1, 0, 0, 0);
        }
    }

    const int col = l & 15;
    const int rbase = row0 + wid * 16 + (l >> 4) * 4;
    #pragma unroll
    for (int reg = 0; reg < 4; reg++) {
        size_t o = ((size_t)blockIdx.y * NN + rbase + reg) * 32;
        partial[o + col]      = acc0[reg];
        partial[o + 16 + col] = acc1[reg];
    }
}

// ------------- Kernel B (fused): partial-sum + BN + ELU -> feat_x, hw1, attn scalars -------------
__global__ void k_enc_prep(
    const float* __restrict__ partial,
    const float* __restrict__ e0b, const float* __restrict__ e0g,
    const float* __restrict__ e0beta, const float* __restrict__ e0m,
    const float* __restrict__ e0v,
    const float* __restrict__ e1w, const float* __restrict__ e1b,
    const float* __restrict__ e1g, const float* __restrict__ e1beta,
    const float* __restrict__ e1m, const float* __restrict__ e1v,
    const float* __restrict__ g1w, const float* __restrict__ g1as,
    const float* __restrict__ g1ad,
    float* __restrict__ out_fx, float* __restrict__ hw1,
    float* __restrict__ s1src, float* __restrict__ s1dst)
{
    int row = blockIdx.x * 256 + threadIdx.x;
    if (row >= NN) return;
    float hr[32];
    #pragma unroll
    for (int c4 = 0; c4 < 8; c4++) {
        float4 p0 = *(const float4*)&partial[(size_t)row * 32 + c4 * 4];
        float4 p1 = *(const float4*)&partial[(size_t)NN * 32 + (size_t)row * 32 + c4 * 4];
        #pragma unroll
        for (int j = 0; j < 4; j++) {
            int c = c4 * 4 + j;
            float s = ((j == 0) ? p0.x + p1.x : (j == 1) ? p0.y + p1.y
                     : (j == 2) ? p0.z + p1.z : p0.w + p1.w);
            float sc = e0g[c] * rsqrtf(e0v[c] + 1e-3f);
            hr[c] = elu((s + e0b[c]) * sc + (e0beta[c] - e0m[c] * sc));
        }
    }
    float fx[20];
    #pragma unroll
    for (int c = 0; c < 20; c++) {
        float s = e1b[c];
        for (int k = 0; k < 32; k++) s += hr[k] * e1w[k * 20 + c];
        float sc = e1g[c] * rsqrtf(e1v[c] + 1e-3f);
        s = (s - e1m[c]) * sc + e1beta[c];
        fx[c] = elu(s);
        out_fx[(size_t)row * 20 + c] = fx[c];
    }
    float ss = 0.f, sd = 0.f;
    for (int c = 0; c < 64; c++) {
        float s = 0.f;
        for (int k = 0; k < 20; k++) s += fx[k] * g1w[k * 64 + c];
        hw1[(size_t)row * 64 + c] = s;
        ss += s * g1as[c];
        sd += s * g1ad[c];
    }
    s1src[row] = ss; s1dst[row] = sd;
}

// ------------- GAT1 gather: one wave per dst, 64 lanes = features; 4-deep pipelined -------------
__global__ __launch_bounds__(256) void k_gat1_gather(
    const int* __restrict__ start, const int* __restrict__ deg,
    const int* __restrict__ srcs,
    const float* __restrict__ s1src, const float* __restrict__ s1dst,
    const float* __restrict__ hw1,
    float* __restrict__ z1, float* __restrict__ acc1)
{
    int d = (blockIdx.x * 256 + threadIdx.x) >> 6;
    int l = threadIdx.x & 63;
    if (d >= NN) return;
    int j0 = start[d], n = deg[d];
    float sd = s1dst[d];
    float acc = 0.f, z = 0.f;
    int j = 0;
    for (; j + 4 <= n; j += 4) {
        int s0 = srcs[j0 + j], s1 = srcs[j0 + j + 1];
        int s2 = srcs[j0 + j + 2], s3 = srcs[j0 + j + 3];
        float a0 = s1src[s0], a1 = s1src[s1], a2 = s1src[s2], a3 = s1src[s3];
        float h0 = hw1[(size_t)s0 * 64 + l], h1 = hw1[(size_t)s1 * 64 + l];
        float h2 = hw1[(size_t)s2 * 64 + l], h3 = hw1[(size_t)s3 * 64 + l];
        float e0 = expf(lrelu(a0 + sd)), e1 = expf(lrelu(a1 + sd));
        float e2 = expf(lrelu(a2 + sd)), e3 = expf(lrelu(a3 + sd));
        z += (e0 + e1) + (e2 + e3);
        acc += e0 * h0; acc += e1 * h1; acc += e2 * h2; acc += e3 * h3;
    }
    for (; j < n; j++) {
        int s = srcs[j0 + j];
        float ex = expf(lrelu(s1src[s] + sd));
        z += ex;
        acc += ex * hw1[(size_t)s * 64 + l];
    }
    acc1[(size_t)d * 64 + l] = acc;
    if (l == 0) z1[d] = z;
}

// ------------- Kernel E: normalize GAT1, BN+ReLU -> c; hw_m/hw_v + scalars -------------
__global__ void k_gat1_norm(
    const float* __restrict__ acc1, const float* __restrict__ z1,
    const float* __restrict__ g1b,
    const float* __restrict__ bncg, const float* __restrict__ bncbeta,
    const float* __restrict__ bncm, const float* __restrict__ bncv,
    const float* __restrict__ gmw, const float* __restrict__ gmas, const float* __restrict__ gmad,
    const float* __restrict__ gvw, const float* __restrict__ gvas, const float* __restrict__ gvad,
    float* __restrict__ hwm, float* __restrict__ hwv,
    float* __restrict__ smsrc, float* __restrict__ smdst,
    float* __restrict__ svsrc, float* __restrict__ svdst)
{
    int row = blockIdx.x * 256 + threadIdx.x;
    if (row >= NN) return;
    float zi = 1.f / (z1[row] + 1e-16f);
    float c[64];
    for (int f = 0; f < 64; f++) {
        float val = acc1[(size_t)row * 64 + f] * zi + g1b[f];
        float sc = bncg[f] * rsqrtf(bncv[f] + 1e-5f);
        val = (val - bncm[f]) * sc + bncbeta[f];
        c[f] = val > 0.f ? val : 0.f;
    }
    float ssm = 0.f, sdm = 0.f, ssv = 0.f, sdv = 0.f;
    for (int o = 0; o < 8; o++) {
        float sm = 0.f, sv = 0.f;
        for (int k = 0; k < 64; k++) {
            sm += c[k] * gmw[k * 8 + o];
            sv += c[k] * gvw[k * 8 + o];
        }
        hwm[(size_t)row * 8 + o] = sm; hwv[(size_t)row * 8 + o] = sv;
        ssm += sm * gmas[o]; sdm += sm * gmad[o];
        ssv += sv * gvas[o]; sdv += sv * gvad[o];
    }
    smsrc[row] = ssm; smdst[row] = sdm;
    svsrc[row] = ssv; svdst[row] = sdv;
}

// ------------- GAT2/3 gather: one wave per dst; lanes = 16 feat (8m+8v) x 4 edge-groups -------------
__global__ __launch_bounds__(256) void k_gat23_gather(
    const int* __restrict__ start, const int* __restrict__ deg,
    const int* __restrict__ srcs,
    const float* __restrict__ smsrc, const float* __restrict__ smdst,
    const float* __restrict__ svsrc, const float* __restrict__ svdst,
    const float* __restrict__ hwm, const float* __restrict__ hwv,
    float* __restrict__ zm, float* __restrict__ accm,
    float* __restrict__ zv, float* __restrict__ accv)
{
    int d = (blockIdx.x * 256 + threadIdx.x) >> 6;
    int l = threadIdx.x & 63;
    if (d >= NN) return;
    const int eg = l >> 4;
    const bool isv = (l & 15) >= 8;
    const int f = l & 7;
    int j0 = start[d], n = deg[d];
    float sdst = isv ? svdst[d] : smdst[d];
    float acc = 0.f, z = 0.f;
    for (int j = eg; j < n; j += 4) {
        int s = srcs[j0 + j];
        float a = (isv ? svsrc[s] : smsrc[s]) + sdst;
        float ex = expf(lrelu(a));
        z += ex;
        float hv = isv ? hwv[(size_t)s * 8 + f] : hwm[(size_t)s * 8 + f];
        acc += ex * hv;
    }
    acc += __shfl_xor(acc, 16); acc += __shfl_xor(acc, 32);
    z   += __shfl_xor(z, 16);   z   += __shfl_xor(z, 32);
    if (l < 16) {
        if (!isv) { accm[(size_t)d * 8 + f] = acc; if (f == 0) zm[d] = z; }
        else      { accv[(size_t)d * 8 + f] = acc; if (f == 0) zv[d] = z; }
    }
}

// ------------- Kernel H: mu/logvar/gnn_z/z, decoder L0 (-> bf16 A-frags), student-t q -------------
__global__ void k_final(
    const float* __restrict__ accm, const float* __restrict__ zm, const float* __restrict__ gmb,
    const float* __restrict__ accv, const float* __restrict__ zv, const float* __restrict__ gvb,
    const float* __restrict__ epsin, const float* __restrict__ fx_out,
    const float* __restrict__ d0w, const float* __restrict__ d0b,
    const float* __restrict__ d0g, const float* __restrict__ d0beta,
    const float* __restrict__ d0m, const float* __restrict__ d0v,
    const float* __restrict__ cluster,
    float* __restrict__ out_z, float* __restrict__ out_mu, float* __restrict__ out_lv,
    float* __restrict__ out_q, float* __restrict__ out_gz,
    unsigned short* __restrict__ abuf)
{
    int row = blockIdx.x * 256 + threadIdx.x;
    if (row >= NN) return;
    float zvec[28];
    #pragma unroll
    for (int k = 0; k < 20; k++) zvec[k] = fx_out[(size_t)row * 20 + k];
    float zim = 1.f / (zm[row] + 1e-16f);
    float ziv = 1.f / (zv[row] + 1e-16f);
    #pragma unroll
    for (int o = 0; o < 8; o++) {
        float mu = accm[(size_t)row * 8 + o] * zim + gmb[o];
        float lv = accv[(size_t)row * 8 + o] * ziv + gvb[o];
        float gz = epsin[(size_t)row * 8 + o] * expf(lv) + mu;
        out_mu[(size_t)row * 8 + o] = mu;
        out_lv[(size_t)row * 8 + o] = lv;
        out_gz[(size_t)row * 8 + o] = gz;
        zvec[20 + o] = gz;
    }
    #pragma unroll
    for (int k = 0; k < 28; k++) out_z[(size_t)row * 28 + k] = zvec[k];
    // decoder L0 -> dv[32] (static-indexed), emitted as MFMA A-fragments (bf16)
    float dv[32];
    #pragma unroll
    for (int c = 0; c < 32; c++) {
        float s = d0b[c];
        #pragma unroll
        for (int k = 0; k < 28; k++) s += zvec[k] * d0w[k * 32 + c];
        float sc = d0g[c] * rsqrtf(d0v[c] + 1e-3f);
        s = (s - d0m[c]) * sc + d0beta[c];
        dv[c] = elu(s);
    }
    int g = row >> 4, rl = row & 15;
    #pragma unroll
    for (int hh = 0; hh < 4; hh++) {
        uint4 p;
        p.x = f2bf(dv[hh*8+0]) | (f2bf(dv[hh*8+1]) << 16);
        p.y = f2bf(dv[hh*8+2]) | (f2bf(dv[hh*8+3]) << 16);
        p.z = f2bf(dv[hh*8+4]) | (f2bf(dv[hh*8+5]) << 16);
        p.w = f2bf(dv[hh*8+6]) | (f2bf(dv[hh*8+7]) << 16);
        *(uint4*)&abuf[(size_t)g * 512 + (rl + 16 * hh) * 8] = p;
    }
    // student-t q
    float zz = 0.f;
    #pragma unroll
    for (int k = 0; k < 28; k++) zz += zvec[k] * zvec[k];
    float qv[15], qs = 0.f;
    for (int j = 0; j < 15; j++) {
        float cc = 0.f, zc = 0.f;
        for (int k = 0; k < 28; k++) {
            float cv = cluster[j * 28 + k];
            cc += cv * cv; zc += zvec[k] * cv;
        }
        float sq = zz + cc - 2.f * zc;
        if (sq < 0.f) sq = 0.f;
        float qb = 1.f / (1.f + sq * (1.f / 0.9f) + 1e-8f);
        qb = powf(qb, 0.95f);
        qv[j] = qb; qs += qb;
    }
    float qi = 1.f / qs;
    #pragma unroll
    for (int j = 0; j < 15; j++) out_q[(size_t)row * 15 + j] = qv[j] * qi;
}

// ------------- Kernel I: de_feat = d @ out_w + out_b, fragment-direct MFMA (no LDS) -------------
// Wave = row-group g (16 rows); per ct: B-frag global load (L2-hit) + 1 MFMA + stores.
__global__ __launch_bounds__(256) void k_dec_out(
    const unsigned short* __restrict__ abuf, const unsigned short* __restrict__ bfragb,
    const float* __restrict__ ob, float* __restrict__ out_de)
{
    const int tid = threadIdx.x, wid = tid >> 6, l = tid & 63;
    const int g = blockIdx.y * 4 + wid;        // row-group 0..2499
    const int ct0 = blockIdx.x * 8;
    short8 a = *(const short8*)&abuf[(size_t)g * 512 + l * 8];
    const int rw = g * 16 + (l >> 4) * 4;
    const int cl = l & 15;
    #pragma unroll
    for (int c = 0; c < 8; c++) {
        int ct = ct0 + c;
        short8 b = *(const short8*)&bfragb[((size_t)ct * 64 + l) * 8];
        f32x4 acc = {0.f, 0.f, 0.f, 0.f};
        acc = __builtin_amdgcn_mfma_f32_16x16x32_bf16(a, b, acc, 0, 0, 0);
        int col = ct * 16 + cl;
        if (col < DIN) {
            float bias = ob[col];
            #pragma unroll
            for (int reg = 0; reg < 4; reg++)
                out_de[(size_t)(rw + reg) * DIN + col] = acc[reg] + bias;
        }
    }
}

extern "C" void kernel_launch(void* const* d_in, const int* in_sizes, int n_in,
                              void* d_out, int out_size, void* d_ws, size_t ws_size,
                              hipStream_t stream) {
    const float* x      = (const float*)d_in[0];
    const int*   ei     = (const int*)  d_in[1];
    const float* e0_w   = (const float*)d_in[2];
    const float* e0_b   = (const float*)d_in[3];
    const float* e0_g   = (const float*)d_in[4];
    const float* e0_be  = (const float*)d_in[5];
    const float* e0_m   = (const float*)d_in[6];
    const float* e0_v   = (const float*)d_in[7];
    const float* e1_w   = (const float*)d_in[8];
    const float* e1_b   = (const float*)d_in[9];
    const float* e1_g   = (const float*)d_in[10];
    const float* e1_be  = (const float*)d_in[11];
    const float* e1_m   = (const float*)d_in[12];
    const float* e1_v   = (const float*)d_in[13];
    const float* g1_w   = (const float*)d_in[14];
    const float* g1_as  = (const float*)d_in[15];
    const float* g1_ad  = (const float*)d_in[16];
    const float* g1_b   = (const float*)d_in[17];
    const float* bnc_g  = (const float*)d_in[18];
    const float* bnc_be = (const float*)d_in[19];
    const float* bnc_m  = (const float*)d_in[20];
    const float* bnc_v  = (const float*)d_in[21];
    const float* gm_w   = (const float*)d_in[22];
    const float* gm_as  = (const float*)d_in[23];
    const float* gm_ad  = (const float*)d_in[24];
    const float* gm_b   = (const float*)d_in[25];
    const float* gv_w   = (const float*)d_in[26];
    const float* gv_as  = (const float*)d_in[27];
    const float* gv_ad  = (const float*)d_in[28];
    const float* gv_b   = (const float*)d_in[29];
    const float* d0_w   = (const float*)d_in[30];
    const float* d0_b   = (const float*)d_in[31];
    const float* d0_g   = (const float*)d_in[32];
    const float* d0_be  = (const float*)d_in[33];
    const float* d0_m   = (const float*)d_in[34];
    const float* d0_v   = (const float*)d_in[35];
    const float* out_w  = (const float*)d_in[36];
    const float* out_b  = (const float*)d_in[37];
    const float* cluster= (const float*)d_in[38];
    const float* epsin  = (const float*)d_in[39];

    float* out = (float*)d_out;
    // output offsets (floats), return order: z, mu, logvar, de_feat, q, feat_x, gnn_z
    float* out_z  = out;
    float* out_mu = out + (size_t)NN * 28;
    float* out_lv = out + (size_t)NN * 36;
    float* out_de = out + (size_t)NN * 44;
    float* out_q  = out + (size_t)NN * 44 + (size_t)NN * DIN;
    float* out_fx = out + (size_t)NN * 59 + (size_t)NN * DIN;
    float* out_gz = out + (size_t)NN * 79 + (size_t)NN * DIN;

    float* ws = (float*)d_ws;
    const size_t n = NN;
    // phase-1 layout
    float* partial = ws;                       // [2][N][32] = 0..64N
    float* hw1     = ws + 64 * n;              // 64N..128N
    float* s1src   = ws + 128 * n;
    float* s1dst   = ws + 129 * n;
    float* z1      = ws + 130 * n;
    unsigned short* abuf   = (unsigned short*)(ws + 131 * n);           // NN*32 bf16 (16N floats)
    unsigned short* wTb    = (unsigned short*)(ws + 147 * n);           // 32*KPAD bf16 (49152 floats)
    unsigned short* bfragb = (unsigned short*)(ws + 147 * n + 49152);   // NCT*64*8 bf16 (49152 floats)
    // phase-1b: acc1 reuses partial region (partial dead after k_enc_prep)
    float* acc1 = ws;                          // 0..64N
    // phase-2 (after gat1_gather; hw1 dead -> overwrite)
    float* hwm   = ws + 64 * n;                // 64N..72N
    float* hwv   = ws + 72 * n;                // 72N..80N
    float* smsrc = ws + 80 * n;
    float* smdst = ws + 81 * n;
    float* svsrc = ws + 82 * n;
    float* svdst = ws + 83 * n;
    float* zm    = ws + 84 * n;
    float* zv    = ws + 85 * n;
    float* accm  = ws + 86 * n;                // 86N..94N
    float* accv  = ws + 94 * n;                // 94N..102N

    // CSR scratch lives in the de_feat output region (overwritten last by k_dec_out)
    int* srcs  = (int*)out_de;         // ET
    int* deg   = srcs + ET;            // NN
    int* cnt   = deg + NN;             // NN
    int* start = cnt + NN;             // NN

    const int NB_ROWS = (NN + 255) / 256;  // 157
    const int NB_E    = (ET + 255) / 256;

    // CSR build
    k_zero<<<(2 * NN + 255) / 256, 256, 0, stream>>>(deg, 2 * NN);   // deg + cnt
    k_deg<<<NB_E, 256, 0, stream>>>(ei, deg);
    k_scan<<<1, 1024, 0, stream>>>(deg, start);
    k_fill<<<NB_E, 256, 0, stream>>>(ei, start, cnt, srcs);

    // weight preps (enc0 B + dec B-frags)
    k_prep_w<<<(32 * KPAD + NCT * 64 + 255) / 256, 256, 0, stream>>>(e0_w, out_w, wTb, bfragb);

    // encoder
    dim3 enc0_grid(NN / 64, NCH);   // 625 x 2
    k_enc0<<<enc0_grid, 256, 0, stream>>>(x, wTb, partial);
    k_enc_prep<<<NB_ROWS, 256, 0, stream>>>(partial, e0_b, e0_g, e0_be, e0_m, e0_v,
                                            e1_w, e1_b, e1_g, e1_be, e1_m, e1_v,
                                            g1_w, g1_as, g1_ad,
                                            out_fx, hw1, s1src, s1dst);
    // GAT1 (gather, 4-deep pipelined, no atomics)
    k_gat1_gather<<<(NN * 64 + 255) / 256, 256, 0, stream>>>(start, deg, srcs,
                                                             s1src, s1dst, hw1, z1, acc1);
    k_gat1_norm<<<NB_ROWS, 256, 0, stream>>>(acc1, z1, g1_b, bnc_g, bnc_be, bnc_m, bnc_v,
                                             gm_w, gm_as, gm_ad, gv_w, gv_as, gv_ad,
                                             hwm, hwv, smsrc, smdst, svsrc, svdst);
    // GAT mu/logvar (gather)
    k_gat23_gather<<<(NN * 64 + 255) / 256, 256, 0, stream>>>(start, deg, srcs,
                                                              smsrc, smdst, svsrc, svdst,
                                                              hwm, hwv, zm, accm, zv, accv);
    k_final<<<NB_ROWS, 256, 0, stream>>>(accm, zm, gm_b, accv, zv, gv_b, epsin, out_fx,
                                         d0_w, d0_b, d0_g, d0_be, d0_m, d0_v, cluster,
                                         out_z, out_mu, out_lv, out_q, out_gz, abuf);
    // decoder out (fragment-direct MFMA)
    dim3 dec_grid(NCT / 8, NN / 64);   // 24 x 625
    k_dec_out<<<dec_grid, 256, 0, stream>>>(abuf, bfragb, out_b, out_de);
}